// Round 1
// baseline (877.030 us; speedup 1.0000x reference)
//
#include <hip/hip_runtime.h>
#include <math.h>

#define EPS_BN 1e-5

namespace {

constexpr double CNT1 = 4096.0 * 1024.0;  // layer1 BN count: B*32*32
constexpr double CNT2 = 4096.0 * 256.0;   // layer2 BN count: B*16*16

// workspace layout (bytes). Required ws >= ~134.3 MB.
constexpr size_t OFF_H1 = 0;            // [4096,16,16,16] f32 = 67,108,864
constexpr size_t OFF_Y2 = 67108864;     // [4096,16,16,16] f32 = 67,108,864
constexpr size_t OFF_H2 = 0;            // [4096,2048] f32 (reuses h1 after conv2)
constexpr size_t OFF_A1 = 33554432;     // [4096,512] f32
constexpr size_t OFF_A2 = 41943040;     // [4096,512] f32
constexpr size_t OFF_ST = 134217728;    // 96 doubles of BN stats

__device__ __forceinline__ float wave_sum(float v) {
#pragma unroll
  for (int o = 32; o > 0; o >>= 1) v += __shfl_down(v, o, 64);
  return v;
}

// per-thread (s,q) per channel -> wave shuffle -> LDS across 4 waves -> 1 f64 atomic/value
template <int NCH>
__device__ __forceinline__ void block_stats_atomic(const float* s, const float* q,
                                                   double* __restrict__ st) {
  __shared__ float red[4][NCH * 2];
  const int lane = threadIdx.x & 63, wid = threadIdx.x >> 6;
#pragma unroll
  for (int c = 0; c < NCH; ++c) {
    float sv = wave_sum(s[c]);
    float qv = wave_sum(q[c]);
    if (lane == 0) { red[wid][2 * c] = sv; red[wid][2 * c + 1] = qv; }
  }
  __syncthreads();
  if (threadIdx.x < NCH * 2) {
    float v = red[0][threadIdx.x] + red[1][threadIdx.x] + red[2][threadIdx.x] +
              red[3][threadIdx.x];
    unsafeAtomicAdd(st + threadIdx.x, (double)v);
  }
}

// ---------------- layer 1: conv 3x3, 3->8, on 32x32, pad 1 -------------------
// x image staged zero-padded into LDS [3][34][34]; weights transposed [27][8].

#define CONV1_STAGE()                                                          \
  __shared__ __align__(16) float xs[3 * 34 * 34];                              \
  __shared__ __align__(16) float wk[216];                                      \
  const int tid = threadIdx.x, n = blockIdx.x;                                 \
  for (int i = tid; i < 3 * 34 * 34; i += 256) xs[i] = 0.f;                    \
  if (tid < 216) wk[(tid % 27) * 8 + tid / 27] = w1[tid];                      \
  __syncthreads();                                                             \
  {                                                                            \
    const float* xp = x + (size_t)n * 3072;                                    \
    for (int i = tid; i < 3072; i += 256) {                                    \
      int ci = i >> 10, r = (i >> 5) & 31, c = i & 31;                         \
      xs[ci * 1156 + (r + 1) * 34 + (c + 1)] = xp[i];                          \
    }                                                                          \
  }                                                                            \
  __syncthreads();

// conv over 4 pixels/thread at rows {ty, ty+8, ty+16, ty+24}, col tx
#define CONV1_COMPUTE_ROWS()                                                   \
  const int tx = tid & 31, ty = tid >> 5;                                      \
  float acc[4][8];                                                             \
  _Pragma("unroll") for (int p = 0; p < 4; ++p)                                \
      _Pragma("unroll") for (int co = 0; co < 8; ++co) acc[p][co] = 0.f;       \
  _Pragma("unroll") for (int ci = 0; ci < 3; ++ci)                             \
      _Pragma("unroll") for (int dy = 0; dy < 3; ++dy)                         \
      _Pragma("unroll") for (int dx = 0; dx < 3; ++dx) {                       \
    const int j = ci * 9 + dy * 3 + dx;                                        \
    float wv[8];                                                               \
    *(float4*)&wv[0] = *(const float4*)&wk[j * 8];                             \
    *(float4*)&wv[4] = *(const float4*)&wk[j * 8 + 4];                         \
    _Pragma("unroll") for (int p = 0; p < 4; ++p) {                            \
      float xv = xs[ci * 1156 + (ty + 8 * p + dy) * 34 + (tx + dx)];           \
      _Pragma("unroll") for (int co = 0; co < 8; ++co) acc[p][co] += xv * wv[co]; \
    }                                                                          \
  }

__global__ __launch_bounds__(256) void k_conv1_stats(
    const float* __restrict__ x, const float* __restrict__ w1,
    double* __restrict__ st1) {
  CONV1_STAGE();
  CONV1_COMPUTE_ROWS();
  float s[8], q[8];
#pragma unroll
  for (int co = 0; co < 8; ++co) {
    float ss = 0.f, qq = 0.f;
#pragma unroll
    for (int p = 0; p < 4; ++p) { float v = acc[p][co]; ss += v; qq += v * v; }
    s[co] = ss; q[co] = qq;
  }
  block_stats_atomic<8>(s, q, st1);
}

__global__ __launch_bounds__(256) void k_conv1_xr(
    const float* __restrict__ x, const float* __restrict__ w1,
    const float* __restrict__ g1, const float* __restrict__ b1,
    const double* __restrict__ st1, double* __restrict__ st2) {
  CONV1_STAGE();
  CONV1_COMPUTE_ROWS();
  float m1[8], inv1[8], gg[8], bb[8];
#pragma unroll
  for (int co = 0; co < 8; ++co) {
    double sd = st1[2 * co], qd = st1[2 * co + 1];
    double md = sd / CNT1;
    m1[co] = (float)md;
    inv1[co] = (float)(1.0 / sqrt(qd / CNT1 - md * md + (double)EPS_BN));
    gg[co] = g1[co]; bb[co] = b1[co];
  }
  float s[8], q[8];
#pragma unroll
  for (int co = 0; co < 8; ++co) {
    float ss = 0.f, qq = 0.f;
#pragma unroll
    for (int p = 0; p < 4; ++p) {
      float xr = fmaxf((acc[p][co] - m1[co]) * inv1[co] * gg[co] + bb[co], 0.f);
      ss += xr; qq += xr * xr;
    }
    s[co] = ss; q[co] = qq;
  }
  block_stats_atomic<8>(s, q, st2);
}

// conv1 + BN1 + relu + scale-expand + BN2 + relu + 2x2 maxpool -> h1
__global__ __launch_bounds__(256) void k_conv1_out(
    const float* __restrict__ x, const float* __restrict__ w1,
    const float* __restrict__ g1, const float* __restrict__ b1,
    const float* __restrict__ dsew, const float* __restrict__ bng,
    const float* __restrict__ bnb, const double* __restrict__ st1,
    const double* __restrict__ st2, float* __restrict__ h1) {
  CONV1_STAGE();
  // 2x2 pixel quad per thread: out pixel (ty, tx) of 16x16
  const int tx = tid & 15, ty = tid >> 4;
  float acc[4][8];
#pragma unroll
  for (int p = 0; p < 4; ++p)
#pragma unroll
    for (int co = 0; co < 8; ++co) acc[p][co] = 0.f;
#pragma unroll
  for (int ci = 0; ci < 3; ++ci)
#pragma unroll
    for (int dy = 0; dy < 3; ++dy)
#pragma unroll
      for (int dx = 0; dx < 3; ++dx) {
        const int j = ci * 9 + dy * 3 + dx;
        float wv[8];
        *(float4*)&wv[0] = *(const float4*)&wk[j * 8];
        *(float4*)&wv[4] = *(const float4*)&wk[j * 8 + 4];
#pragma unroll
        for (int p = 0; p < 4; ++p) {
          const int pr = p >> 1, pc = p & 1;
          float xv = xs[ci * 1156 + (2 * ty + pr + dy) * 34 + (2 * tx + pc + dx)];
#pragma unroll
          for (int co = 0; co < 8; ++co) acc[p][co] += xv * wv[co];
        }
      }
#pragma unroll
  for (int i = 0; i < 8; ++i) {
    double sd = st1[2 * i], qd = st1[2 * i + 1];
    double md = sd / CNT1;
    float m1 = (float)md;
    float inv1 = (float)(1.0 / sqrt(qd / CNT1 - md * md + (double)EPS_BN));
    float gg = g1[i], bb = b1[i];
    double s2d = st2[2 * i], q2d = st2[2 * i + 1];
    double mxd = s2d / CNT1;
    double vxd = q2d / CNT1 - mxd * mxd;
    float xr[4];
#pragma unroll
    for (int p = 0; p < 4; ++p)
      xr[p] = fmaxf((acc[p][i] - m1) * inv1 * gg + bb, 0.f);
#pragma unroll
    for (int g = 0; g < 2; ++g) {
      const int c = 2 * i + g;
      float w = dsew[i * 2 + g];
      float m2 = (float)(w * mxd);
      float inv2 = (float)(1.0 / sqrt((double)w * w * vxd + (double)EPS_BN));
      float gam = bng[c], bet = bnb[c];
      float r0 = fmaxf((xr[0] * w - m2) * inv2 * gam + bet, 0.f);
      float r1 = fmaxf((xr[1] * w - m2) * inv2 * gam + bet, 0.f);
      float r2 = fmaxf((xr[2] * w - m2) * inv2 * gam + bet, 0.f);
      float r3 = fmaxf((xr[3] * w - m2) * inv2 * gam + bet, 0.f);
      h1[(size_t)(n * 16 + c) * 256 + ty * 16 + tx] =
          fmaxf(fmaxf(r0, r1), fmaxf(r2, r3));
    }
  }
}

// ---------------- layer 2: conv 3x3, 16->16, on 16x16, pad 1 -----------------
// 2 images per block; y2 (raw conv out) materialized + stats.
__global__ __launch_bounds__(256) void k_conv2_stats(
    const float* __restrict__ h1, const float* __restrict__ w2,
    float* __restrict__ y2, double* __restrict__ st3) {
  __shared__ __align__(16) float hs[2][16 * 18 * 18];
  __shared__ __align__(16) float wt[2304];  // [ci][k][co], co contiguous
  const int tid = threadIdx.x, n0 = blockIdx.x * 2;
  for (int i = tid; i < 2 * 5184; i += 256) (&hs[0][0])[i] = 0.f;
  for (int i = tid; i < 2304; i += 256) {
    int co = i & 15, r = i >> 4, ci = r / 9, k = r % 9;
    wt[i] = w2[(co * 16 + ci) * 9 + k];
  }
  __syncthreads();
#pragma unroll
  for (int img = 0; img < 2; ++img) {
    const float* hp = h1 + (size_t)(n0 + img) * 4096;
    for (int i = tid; i < 4096; i += 256) {
      int ci = i >> 8, r = (i >> 4) & 15, c = i & 15;
      hs[img][ci * 324 + (r + 1) * 18 + (c + 1)] = hp[i];
    }
  }
  __syncthreads();
  const int tx = tid & 15, ty = tid >> 4;
  float acc[2][16];
#pragma unroll
  for (int img = 0; img < 2; ++img)
#pragma unroll
    for (int co = 0; co < 16; ++co) acc[img][co] = 0.f;
  for (int ci = 0; ci < 16; ++ci) {
#pragma unroll
    for (int k = 0; k < 9; ++k) {
      const int dy = k / 3, dx = k % 3;
      float wv[16];
      const float4* wp = (const float4*)&wt[(ci * 9 + k) * 16];
      *(float4*)&wv[0] = wp[0];
      *(float4*)&wv[4] = wp[1];
      *(float4*)&wv[8] = wp[2];
      *(float4*)&wv[12] = wp[3];
      float xa = hs[0][ci * 324 + (ty + dy) * 18 + (tx + dx)];
      float xb = hs[1][ci * 324 + (ty + dy) * 18 + (tx + dx)];
#pragma unroll
      for (int co = 0; co < 16; ++co) {
        acc[0][co] += xa * wv[co];
        acc[1][co] += xb * wv[co];
      }
    }
  }
  float s[16], q[16];
#pragma unroll
  for (int co = 0; co < 16; ++co) {
    float va = acc[0][co], vb = acc[1][co];
    y2[(size_t)(n0 * 16 + co) * 256 + tid] = va;
    y2[(size_t)((n0 + 1) * 16 + co) * 256 + tid] = vb;
    s[co] = va + vb; q[co] = va * va + vb * vb;
  }
  block_stats_atomic<16>(s, q, st3);
}

// stats of xr2 = relu(bn(y2)); one (channel, 16-image-chunk) per block
__global__ __launch_bounds__(256) void k_xr2_stats(
    const float* __restrict__ y2, const float* __restrict__ g2,
    const float* __restrict__ b2, const double* __restrict__ st3,
    double* __restrict__ st4) {
  const int c = blockIdx.x & 15, n0 = (blockIdx.x >> 4) << 4;
  double sd = st3[2 * c], qd = st3[2 * c + 1];
  double md = sd / CNT2;
  float m = (float)md;
  float inv = (float)(1.0 / sqrt(qd / CNT2 - md * md + (double)EPS_BN));
  float gg = g2[c], bb = b2[c];
  float s = 0.f, q = 0.f;
#pragma unroll
  for (int k = 0; k < 16; ++k) {
    float v = y2[((size_t)(n0 + k) * 16 + c) * 256 + threadIdx.x];
    float xr = fmaxf((v - m) * inv * gg + bb, 0.f);
    s += xr; q += xr * xr;
  }
  block_stats_atomic<1>(&s, &q, st4 + 2 * c);
}

// y2 -> BN+relu -> scale-expand -> BN+relu -> 2x2 maxpool -> h2 [4096][2048]
__global__ __launch_bounds__(256) void k_l2_out(
    const float* __restrict__ y2, const float* __restrict__ g2,
    const float* __restrict__ b2, const float* __restrict__ dsew,
    const float* __restrict__ bng, const float* __restrict__ bnb,
    const double* __restrict__ st3, const double* __restrict__ st4,
    float* __restrict__ h2) {
  const int sub = threadIdx.x >> 6, lane = threadIdx.x & 63;
  const int n = blockIdx.x * 4 + sub;
  const int px = lane & 7, py = lane >> 3;
#pragma unroll
  for (int i = 0; i < 16; ++i) {
    double sd = st3[2 * i], qd = st3[2 * i + 1];
    double md = sd / CNT2;
    float m3 = (float)md;
    float inv3 = (float)(1.0 / sqrt(qd / CNT2 - md * md + (double)EPS_BN));
    float gg = g2[i], bb = b2[i];
    double s4 = st4[2 * i], q4 = st4[2 * i + 1];
    double mxd = s4 / CNT2;
    double vxd = q4 / CNT2 - mxd * mxd;
    const size_t base = ((size_t)n * 16 + i) * 256;
    float2 v01 = *(const float2*)&y2[base + (2 * py) * 16 + 2 * px];
    float2 v23 = *(const float2*)&y2[base + (2 * py + 1) * 16 + 2 * px];
    float xr0 = fmaxf((v01.x - m3) * inv3 * gg + bb, 0.f);
    float xr1 = fmaxf((v01.y - m3) * inv3 * gg + bb, 0.f);
    float xr2 = fmaxf((v23.x - m3) * inv3 * gg + bb, 0.f);
    float xr3 = fmaxf((v23.y - m3) * inv3 * gg + bb, 0.f);
#pragma unroll
    for (int g = 0; g < 2; ++g) {
      const int c = 2 * i + g;
      float w = dsew[i * 2 + g];
      float m4 = (float)(w * mxd);
      float inv4 = (float)(1.0 / sqrt((double)w * w * vxd + (double)EPS_BN));
      float gam = bng[c], bet = bnb[c];
      float r0 = fmaxf((xr0 * w - m4) * inv4 * gam + bet, 0.f);
      float r1 = fmaxf((xr1 * w - m4) * inv4 * gam + bet, 0.f);
      float r2 = fmaxf((xr2 * w - m4) * inv4 * gam + bet, 0.f);
      float r3 = fmaxf((xr3 * w - m4) * inv4 * gam + bet, 0.f);
      h2[(size_t)n * 2048 + c * 64 + py * 8 + px] =
          fmaxf(fmaxf(r0, r1), fmaxf(r2, r3));
    }
  }
}

// ---------------- FC: C[M,N] = act(A[M,K] @ W[N,K]^T + b) --------------------
// 64x64 tile, 256 threads, 4x4 microtile, kt=16.
__global__ __launch_bounds__(256) void k_fc_gemm(
    const float* __restrict__ A, const float* __restrict__ W,
    const float* __restrict__ bias, float* __restrict__ C, int N, int K,
    int relu) {
  __shared__ __align__(16) float As[16][64];
  __shared__ __align__(16) float Bs[16][64];
  const int tid = threadIdx.x;
  const int bm = blockIdx.y * 64, bn = blockIdx.x * 64;
  const int row = tid >> 2;
  const int kq = (tid & 3) * 4;
  const int ty = tid >> 4, tx = tid & 15;
  float acc[4][4];
#pragma unroll
  for (int i = 0; i < 4; ++i)
#pragma unroll
    for (int j = 0; j < 4; ++j) acc[i][j] = 0.f;
  for (int kk = 0; kk < K; kk += 16) {
    float4 av = *(const float4*)&A[(size_t)(bm + row) * K + kk + kq];
    float4 bv = *(const float4*)&W[(size_t)(bn + row) * K + kk + kq];
    As[kq + 0][row] = av.x; As[kq + 1][row] = av.y;
    As[kq + 2][row] = av.z; As[kq + 3][row] = av.w;
    Bs[kq + 0][row] = bv.x; Bs[kq + 1][row] = bv.y;
    Bs[kq + 2][row] = bv.z; Bs[kq + 3][row] = bv.w;
    __syncthreads();
#pragma unroll
    for (int k = 0; k < 16; ++k) {
      float4 a = *(const float4*)&As[k][ty * 4];
      float4 b = *(const float4*)&Bs[k][tx * 4];
      acc[0][0] += a.x * b.x; acc[0][1] += a.x * b.y;
      acc[0][2] += a.x * b.z; acc[0][3] += a.x * b.w;
      acc[1][0] += a.y * b.x; acc[1][1] += a.y * b.y;
      acc[1][2] += a.y * b.z; acc[1][3] += a.y * b.w;
      acc[2][0] += a.z * b.x; acc[2][1] += a.z * b.y;
      acc[2][2] += a.z * b.z; acc[2][3] += a.z * b.w;
      acc[3][0] += a.w * b.x; acc[3][1] += a.w * b.y;
      acc[3][2] += a.w * b.z; acc[3][3] += a.w * b.w;
    }
    __syncthreads();
  }
  float4 bia = *(const float4*)&bias[bn + tx * 4];
#pragma unroll
  for (int i = 0; i < 4; ++i) {
    const int m = bm + ty * 4 + i;
    float4 v;
    v.x = acc[i][0] + bia.x; v.y = acc[i][1] + bia.y;
    v.z = acc[i][2] + bia.z; v.w = acc[i][3] + bia.w;
    if (relu) {
      v.x = fmaxf(v.x, 0.f); v.y = fmaxf(v.y, 0.f);
      v.z = fmaxf(v.z, 0.f); v.w = fmaxf(v.w, 0.f);
    }
    *(float4*)&C[(size_t)m * N + bn + tx * 4] = v;
  }
}

// fc3: one wave per row, N=10, K=512
__global__ __launch_bounds__(256) void k_fc3(const float* __restrict__ A,
                                             const float* __restrict__ W,
                                             const float* __restrict__ b,
                                             float* __restrict__ out) {
  const int wid = threadIdx.x >> 6, lane = threadIdx.x & 63;
  const int row = blockIdx.x * 4 + wid;
  float p[10];
#pragma unroll
  for (int o = 0; o < 10; ++o) p[o] = 0.f;
  const float* a = A + (size_t)row * 512;
#pragma unroll
  for (int jj = 0; jj < 8; ++jj) {
    const int j = lane + jj * 64;
    float av = a[j];
#pragma unroll
    for (int o = 0; o < 10; ++o) p[o] += av * W[o * 512 + j];
  }
#pragma unroll
  for (int o = 0; o < 10; ++o) p[o] = wave_sum(p[o]);
  if (lane == 0) {
#pragma unroll
    for (int o = 0; o < 10; ++o) out[(size_t)row * 10 + o] = p[o] + b[o];
  }
}

}  // namespace

extern "C" void kernel_launch(void* const* d_in, const int* in_sizes, int n_in,
                              void* d_out, int out_size, void* d_ws,
                              size_t ws_size, hipStream_t stream) {
  const float* x      = (const float*)d_in[0];
  const float* dfe1_w = (const float*)d_in[1];
  const float* dse1_g = (const float*)d_in[2];
  const float* dse1_b = (const float*)d_in[3];
  const float* dse1_w = (const float*)d_in[4];
  const float* bn1_g  = (const float*)d_in[5];
  const float* bn1_b  = (const float*)d_in[6];
  const float* dfe2_w = (const float*)d_in[7];
  const float* dse2_g = (const float*)d_in[8];
  const float* dse2_b = (const float*)d_in[9];
  const float* dse2_w = (const float*)d_in[10];
  const float* bn2_g  = (const float*)d_in[11];
  const float* bn2_b  = (const float*)d_in[12];
  const float* fc1_w  = (const float*)d_in[13];
  const float* fc1_b  = (const float*)d_in[14];
  const float* fc2_w  = (const float*)d_in[15];
  const float* fc2_b  = (const float*)d_in[16];
  const float* fc3_w  = (const float*)d_in[17];
  const float* fc3_b  = (const float*)d_in[18];
  float* out = (float*)d_out;
  char* ws = (char*)d_ws;
  float* h1 = (float*)(ws + OFF_H1);
  float* y2 = (float*)(ws + OFF_Y2);
  float* h2 = (float*)(ws + OFF_H2);
  float* a1 = (float*)(ws + OFF_A1);
  float* a2 = (float*)(ws + OFF_A2);
  double* st = (double*)(ws + OFF_ST);  // st1 @0(16), st2 @16(16), st3 @32(32), st4 @64(32)

  hipMemsetAsync(st, 0, 96 * sizeof(double), stream);
  k_conv1_stats<<<4096, 256, 0, stream>>>(x, dfe1_w, st);
  k_conv1_xr<<<4096, 256, 0, stream>>>(x, dfe1_w, dse1_g, dse1_b, st, st + 16);
  k_conv1_out<<<4096, 256, 0, stream>>>(x, dfe1_w, dse1_g, dse1_b, dse1_w,
                                        bn1_g, bn1_b, st, st + 16, h1);
  k_conv2_stats<<<2048, 256, 0, stream>>>(h1, dfe2_w, y2, st + 32);
  k_xr2_stats<<<4096, 256, 0, stream>>>(y2, dse2_g, dse2_b, st + 32, st + 64);
  k_l2_out<<<1024, 256, 0, stream>>>(y2, dse2_g, dse2_b, dse2_w, bn2_g, bn2_b,
                                     st + 32, st + 64, h2);
  k_fc_gemm<<<dim3(8, 64), 256, 0, stream>>>(h2, fc1_w, fc1_b, a1, 512, 2048, 1);
  k_fc_gemm<<<dim3(8, 64), 256, 0, stream>>>(a1, fc2_w, fc2_b, a2, 512, 512, 1);
  k_fc3<<<1024, 256, 0, stream>>>(a2, fc3_w, fc3_b, out);
}

// Round 2
// 630.292 us; speedup vs baseline: 1.3915x; 1.3915x over previous
//
#include <hip/hip_runtime.h>
#include <math.h>

#define EPS_BN 1e-5

namespace {

constexpr double CNT1 = 4096.0 * 1024.0;  // layer1 BN count: B*32*32
constexpr double CNT2 = 4096.0 * 256.0;   // layer2 BN count: B*16*16

// workspace layout (bytes). Required ws >= ~134.3 MB.
constexpr size_t OFF_H1 = 0;            // [4096,16,16,16] f32 = 67,108,864
constexpr size_t OFF_Y2 = 67108864;     // [4096,16,16,16] f32 = 67,108,864
constexpr size_t OFF_H2 = 0;            // [4096,2048] f32 (reuses h1 after conv2)
constexpr size_t OFF_A1 = 33554432;     // [4096,512] f32
constexpr size_t OFF_A2 = 41943040;     // [4096,512] f32
constexpr size_t OFF_ST = 134217728;    // BN stats: 96 slots x 64B (1 double/line)

// stat slot s lives at doubles[s*8] -> one 64B cache line per value, so the
// per-block atomics to different stats pipeline in parallel TCC slots.
#define STG(p, i) (p)[(size_t)(i) * 8]

__device__ __forceinline__ float wave_sum(float v) {
#pragma unroll
  for (int o = 32; o > 0; o >>= 1) v += __shfl_down(v, o, 64);
  return v;
}

// per-thread (s,q) per channel -> wave shuffle -> LDS across 4 waves -> 1 f64
// atomic per value per block (to padded, per-line slots)
template <int NV>
__device__ __forceinline__ void block_stats_atomic(const float* s, const float* q,
                                                   double* __restrict__ st) {
  __shared__ float red[4][NV * 2];
  const int lane = threadIdx.x & 63, wid = threadIdx.x >> 6;
#pragma unroll
  for (int c = 0; c < NV; ++c) {
    float sv = wave_sum(s[c]);
    float qv = wave_sum(q[c]);
    if (lane == 0) { red[wid][2 * c] = sv; red[wid][2 * c + 1] = qv; }
  }
  __syncthreads();
  if (threadIdx.x < NV * 2) {
    float v = red[0][threadIdx.x] + red[1][threadIdx.x] + red[2][threadIdx.x] +
              red[3][threadIdx.x];
    unsafeAtomicAdd(st + (size_t)threadIdx.x * 8, (double)v);
  }
}

// ---------------- layer 1: conv 3x3, 3->8, on 32x32, pad 1 -------------------
// image staged zero-padded into LDS [3][34][34]; weights transposed [27][8].

__device__ __forceinline__ void conv1_stage_img(const float* __restrict__ xp,
                                                float* xs, int tid) {
  for (int i = tid; i < 3072; i += 256) {
    int ci = i >> 10, r = (i >> 5) & 31, c = i & 31;
    xs[ci * 1156 + (r + 1) * 34 + (c + 1)] = xp[i];
  }
}

// 4 pixels/thread at rows {ty, ty+8, ty+16, ty+24}, col tx (tx<32, ty<8)
__device__ __forceinline__ void conv1_compute_rows(const float* xs,
                                                   const float* wk, int tx,
                                                   int ty, float acc[4][8]) {
#pragma unroll
  for (int p = 0; p < 4; ++p)
#pragma unroll
    for (int co = 0; co < 8; ++co) acc[p][co] = 0.f;
#pragma unroll
  for (int ci = 0; ci < 3; ++ci)
#pragma unroll
    for (int dy = 0; dy < 3; ++dy)
#pragma unroll
      for (int dx = 0; dx < 3; ++dx) {
        const int j = ci * 9 + dy * 3 + dx;
        float wv[8];
        *(float4*)&wv[0] = *(const float4*)&wk[j * 8];
        *(float4*)&wv[4] = *(const float4*)&wk[j * 8 + 4];
#pragma unroll
        for (int p = 0; p < 4; ++p) {
          float xv = xs[ci * 1156 + (ty + 8 * p + dy) * 34 + (tx + dx)];
#pragma unroll
          for (int co = 0; co < 8; ++co) acc[p][co] += xv * wv[co];
        }
      }
}

// 2x2 pixel quad per thread at out-pixel (ty, tx) of 16x16 (tx<16, ty<16)
__device__ __forceinline__ void conv1_compute_quad(const float* xs,
                                                   const float* wk, int tx,
                                                   int ty, float acc[4][8]) {
#pragma unroll
  for (int p = 0; p < 4; ++p)
#pragma unroll
    for (int co = 0; co < 8; ++co) acc[p][co] = 0.f;
#pragma unroll
  for (int ci = 0; ci < 3; ++ci)
#pragma unroll
    for (int dy = 0; dy < 3; ++dy)
#pragma unroll
      for (int dx = 0; dx < 3; ++dx) {
        const int j = ci * 9 + dy * 3 + dx;
        float wv[8];
        *(float4*)&wv[0] = *(const float4*)&wk[j * 8];
        *(float4*)&wv[4] = *(const float4*)&wk[j * 8 + 4];
#pragma unroll
        for (int p = 0; p < 4; ++p) {
          const int pr = p >> 1, pc = p & 1;
          float xv = xs[ci * 1156 + (2 * ty + pr + dy) * 34 + (2 * tx + pc + dx)];
#pragma unroll
          for (int co = 0; co < 8; ++co) acc[p][co] += xv * wv[co];
        }
      }
}

// 8 images per block, grid 512
__global__ __launch_bounds__(256) void k_conv1_stats(
    const float* __restrict__ x, const float* __restrict__ w1,
    double* __restrict__ st1) {
  __shared__ __align__(16) float xs[3 * 34 * 34];
  __shared__ __align__(16) float wk[216];
  const int tid = threadIdx.x;
  for (int i = tid; i < 3 * 34 * 34; i += 256) xs[i] = 0.f;
  if (tid < 216) wk[(tid % 27) * 8 + tid / 27] = w1[tid];
  const int tx = tid & 31, ty = tid >> 5;
  float s[8], q[8];
#pragma unroll
  for (int c = 0; c < 8; ++c) { s[c] = 0.f; q[c] = 0.f; }
  for (int img = 0; img < 8; ++img) {
    __syncthreads();
    conv1_stage_img(x + ((size_t)blockIdx.x * 8 + img) * 3072, xs, tid);
    __syncthreads();
    float acc[4][8];
    conv1_compute_rows(xs, wk, tx, ty, acc);
#pragma unroll
    for (int co = 0; co < 8; ++co)
#pragma unroll
      for (int p = 0; p < 4; ++p) {
        float v = acc[p][co];
        s[co] += v; q[co] += v * v;
      }
  }
  block_stats_atomic<8>(s, q, st1);
}

__global__ __launch_bounds__(256) void k_conv1_xr(
    const float* __restrict__ x, const float* __restrict__ w1,
    const float* __restrict__ g1, const float* __restrict__ b1,
    const double* __restrict__ st1, double* __restrict__ st2) {
  __shared__ __align__(16) float xs[3 * 34 * 34];
  __shared__ __align__(16) float wk[216];
  const int tid = threadIdx.x;
  for (int i = tid; i < 3 * 34 * 34; i += 256) xs[i] = 0.f;
  if (tid < 216) wk[(tid % 27) * 8 + tid / 27] = w1[tid];
  // per-channel affine: xr = relu(y * a1 + c1)
  float a1[8], c1[8];
#pragma unroll
  for (int co = 0; co < 8; ++co) {
    double sd = STG(st1, 2 * co), qd = STG(st1, 2 * co + 1);
    double md = sd / CNT1;
    float inv1 = (float)(1.0 / sqrt(qd / CNT1 - md * md + (double)EPS_BN));
    a1[co] = inv1 * g1[co];
    c1[co] = b1[co] - (float)md * a1[co];
  }
  const int tx = tid & 31, ty = tid >> 5;
  float s[8], q[8];
#pragma unroll
  for (int c = 0; c < 8; ++c) { s[c] = 0.f; q[c] = 0.f; }
  for (int img = 0; img < 8; ++img) {
    __syncthreads();
    conv1_stage_img(x + ((size_t)blockIdx.x * 8 + img) * 3072, xs, tid);
    __syncthreads();
    float acc[4][8];
    conv1_compute_rows(xs, wk, tx, ty, acc);
#pragma unroll
    for (int co = 0; co < 8; ++co)
#pragma unroll
      for (int p = 0; p < 4; ++p) {
        float xr = fmaxf(acc[p][co] * a1[co] + c1[co], 0.f);
        s[co] += xr; q[co] += xr * xr;
      }
  }
  block_stats_atomic<8>(s, q, st2);
}

// conv1 + BN1 + relu + scale-expand + BN2 + relu + 2x2 maxpool -> h1
__global__ __launch_bounds__(256) void k_conv1_out(
    const float* __restrict__ x, const float* __restrict__ w1,
    const float* __restrict__ g1, const float* __restrict__ b1,
    const float* __restrict__ dsew, const float* __restrict__ bng,
    const float* __restrict__ bnb, const double* __restrict__ st1,
    const double* __restrict__ st2, float* __restrict__ h1) {
  __shared__ __align__(16) float xs[3 * 34 * 34];
  __shared__ __align__(16) float wk[216];
  __shared__ float cA1[8], cC1[8], cS2[16], cO2[16];
  const int tid = threadIdx.x;
  for (int i = tid; i < 3 * 34 * 34; i += 256) xs[i] = 0.f;
  if (tid < 216) wk[(tid % 27) * 8 + tid / 27] = w1[tid];
  if (tid < 16) {
    const int i = tid >> 1, g = tid & 1;
    double sd = STG(st1, 2 * i), qd = STG(st1, 2 * i + 1);
    double md = sd / CNT1;
    float inv1 = (float)(1.0 / sqrt(qd / CNT1 - md * md + (double)EPS_BN));
    float a1 = inv1 * g1[i];
    if (g == 0) { cA1[i] = a1; cC1[i] = b1[i] - (float)md * a1; }
    double s2 = STG(st2, 2 * i), q2 = STG(st2, 2 * i + 1);
    double mx = s2 / CNT1, vx = q2 / CNT1 - mx * mx;
    float w = dsew[i * 2 + g];
    double inv2 = 1.0 / sqrt((double)w * w * vx + (double)EPS_BN);
    cS2[tid] = (float)(w * inv2) * bng[tid];
    cO2[tid] = bnb[tid] - (float)(w * mx * inv2) * bng[tid];
  }
  const int tx = tid & 15, ty = tid >> 4;
  for (int img = 0; img < 8; ++img) {
    const int n = blockIdx.x * 8 + img;
    __syncthreads();
    conv1_stage_img(x + (size_t)n * 3072, xs, tid);
    __syncthreads();
    float acc[4][8];
    conv1_compute_quad(xs, wk, tx, ty, acc);
#pragma unroll
    for (int i = 0; i < 8; ++i) {
      float xr[4];
#pragma unroll
      for (int p = 0; p < 4; ++p)
        xr[p] = fmaxf(acc[p][i] * cA1[i] + cC1[i], 0.f);
#pragma unroll
      for (int g = 0; g < 2; ++g) {
        const int c = 2 * i + g;
        float sc = cS2[c], of = cO2[c];
        float r0 = fmaxf(xr[0] * sc + of, 0.f);
        float r1 = fmaxf(xr[1] * sc + of, 0.f);
        float r2 = fmaxf(xr[2] * sc + of, 0.f);
        float r3 = fmaxf(xr[3] * sc + of, 0.f);
        h1[(size_t)(n * 16 + c) * 256 + ty * 16 + tx] =
            fmaxf(fmaxf(r0, r1), fmaxf(r2, r3));
      }
    }
  }
}

// ---------------- layer 2: conv 3x3, 16->16, on 16x16, pad 1 -----------------
// 2 images staged at a time, 4 iterations (8 images/block), grid 512.
__global__ __launch_bounds__(256) void k_conv2_stats(
    const float* __restrict__ h1, const float* __restrict__ w2,
    float* __restrict__ y2, double* __restrict__ st3) {
  __shared__ __align__(16) float hs[2][16 * 18 * 18];
  __shared__ __align__(16) float wt[2304];  // [ci][k][co], co contiguous
  const int tid = threadIdx.x;
  for (int i = tid; i < 2 * 5184; i += 256) (&hs[0][0])[i] = 0.f;
  for (int i = tid; i < 2304; i += 256) {
    int co = i & 15, r = i >> 4, ci = r / 9, k = r % 9;
    wt[i] = w2[(co * 16 + ci) * 9 + k];
  }
  const int tx = tid & 15, ty = tid >> 4;
  float s[16], q[16];
#pragma unroll
  for (int c = 0; c < 16; ++c) { s[c] = 0.f; q[c] = 0.f; }
  for (int it = 0; it < 4; ++it) {
    const int n0 = blockIdx.x * 8 + it * 2;
    __syncthreads();
#pragma unroll
    for (int img = 0; img < 2; ++img) {
      const float* hp = h1 + (size_t)(n0 + img) * 4096;
      for (int i = tid; i < 4096; i += 256) {
        int ci = i >> 8, r = (i >> 4) & 15, c = i & 15;
        hs[img][ci * 324 + (r + 1) * 18 + (c + 1)] = hp[i];
      }
    }
    __syncthreads();
    float acc[2][16];
#pragma unroll
    for (int img = 0; img < 2; ++img)
#pragma unroll
      for (int co = 0; co < 16; ++co) acc[img][co] = 0.f;
    for (int ci = 0; ci < 16; ++ci) {
#pragma unroll
      for (int k = 0; k < 9; ++k) {
        const int dy = k / 3, dx = k % 3;
        float wv[16];
        const float4* wp = (const float4*)&wt[(ci * 9 + k) * 16];
        *(float4*)&wv[0] = wp[0];
        *(float4*)&wv[4] = wp[1];
        *(float4*)&wv[8] = wp[2];
        *(float4*)&wv[12] = wp[3];
        float xa = hs[0][ci * 324 + (ty + dy) * 18 + (tx + dx)];
        float xb = hs[1][ci * 324 + (ty + dy) * 18 + (tx + dx)];
#pragma unroll
        for (int co = 0; co < 16; ++co) {
          acc[0][co] += xa * wv[co];
          acc[1][co] += xb * wv[co];
        }
      }
    }
#pragma unroll
    for (int co = 0; co < 16; ++co) {
      float va = acc[0][co], vb = acc[1][co];
      y2[(size_t)(n0 * 16 + co) * 256 + tid] = va;
      y2[(size_t)((n0 + 1) * 16 + co) * 256 + tid] = vb;
      s[co] += va + vb; q[co] += va * va + vb * vb;
    }
  }
  block_stats_atomic<16>(s, q, st3);
}

// stats of xr2 = relu(bn(y2)); one (channel, 16-image-chunk) per block
__global__ __launch_bounds__(256) void k_xr2_stats(
    const float* __restrict__ y2, const float* __restrict__ g2,
    const float* __restrict__ b2, const double* __restrict__ st3,
    double* __restrict__ st4) {
  const int c = blockIdx.x & 15, n0 = (blockIdx.x >> 4) << 4;
  double sd = STG(st3, 2 * c), qd = STG(st3, 2 * c + 1);
  double md = sd / CNT2;
  float m = (float)md;
  float inv = (float)(1.0 / sqrt(qd / CNT2 - md * md + (double)EPS_BN));
  float gg = g2[c], bb = b2[c];
  float s = 0.f, q = 0.f;
#pragma unroll
  for (int k = 0; k < 16; ++k) {
    float v = y2[((size_t)(n0 + k) * 16 + c) * 256 + threadIdx.x];
    float xr = fmaxf((v - m) * inv * gg + bb, 0.f);
    s += xr; q += xr * xr;
  }
  block_stats_atomic<1>(&s, &q, st4 + (size_t)(2 * c) * 8);
}

// y2 -> BN+relu -> scale-expand -> BN+relu -> 2x2 maxpool -> h2 [4096][2048]
__global__ __launch_bounds__(256) void k_l2_out(
    const float* __restrict__ y2, const float* __restrict__ g2,
    const float* __restrict__ b2, const float* __restrict__ dsew,
    const float* __restrict__ bng, const float* __restrict__ bnb,
    const double* __restrict__ st3, const double* __restrict__ st4,
    float* __restrict__ h2) {
  __shared__ float cS3[16], cO3[16], cS4[32], cO4[32];
  const int tid = threadIdx.x;
  if (tid < 32) {
    const int i = tid >> 1, g = tid & 1;
    double sd = STG(st3, 2 * i), qd = STG(st3, 2 * i + 1);
    double md = sd / CNT2;
    float inv3 = (float)(1.0 / sqrt(qd / CNT2 - md * md + (double)EPS_BN));
    float a3 = inv3 * g2[i];
    if (g == 0) { cS3[i] = a3; cO3[i] = b2[i] - (float)md * a3; }
    double s4 = STG(st4, 2 * i), q4 = STG(st4, 2 * i + 1);
    double mx = s4 / CNT2, vx = q4 / CNT2 - mx * mx;
    float w = dsew[2 * i + g];
    double inv4 = 1.0 / sqrt((double)w * w * vx + (double)EPS_BN);
    cS4[tid] = (float)(w * inv4) * bng[tid];
    cO4[tid] = bnb[tid] - (float)(w * mx * inv4) * bng[tid];
  }
  __syncthreads();
  const int sub = tid >> 6, lane = tid & 63;
  const int n = blockIdx.x * 4 + sub;
  const int px = lane & 7, py = lane >> 3;
#pragma unroll
  for (int i = 0; i < 16; ++i) {
    const size_t base = ((size_t)n * 16 + i) * 256;
    float2 v01 = *(const float2*)&y2[base + (2 * py) * 16 + 2 * px];
    float2 v23 = *(const float2*)&y2[base + (2 * py + 1) * 16 + 2 * px];
    float a3 = cS3[i], c3 = cO3[i];
    float xr0 = fmaxf(v01.x * a3 + c3, 0.f);
    float xr1 = fmaxf(v01.y * a3 + c3, 0.f);
    float xr2 = fmaxf(v23.x * a3 + c3, 0.f);
    float xr3 = fmaxf(v23.y * a3 + c3, 0.f);
#pragma unroll
    for (int g = 0; g < 2; ++g) {
      const int c = 2 * i + g;
      float sc = cS4[c], of = cO4[c];
      float r0 = fmaxf(xr0 * sc + of, 0.f);
      float r1 = fmaxf(xr1 * sc + of, 0.f);
      float r2 = fmaxf(xr2 * sc + of, 0.f);
      float r3 = fmaxf(xr3 * sc + of, 0.f);
      h2[(size_t)n * 2048 + c * 64 + py * 8 + px] =
          fmaxf(fmaxf(r0, r1), fmaxf(r2, r3));
    }
  }
}

// ---------------- FC: C[M,N] = act(A[M,K] @ W[N,K]^T + b) --------------------
// 64x64 tile, 256 threads, 4x4 microtile, kt=16.
__global__ __launch_bounds__(256) void k_fc_gemm(
    const float* __restrict__ A, const float* __restrict__ W,
    const float* __restrict__ bias, float* __restrict__ C, int N, int K,
    int relu) {
  __shared__ __align__(16) float As[16][64];
  __shared__ __align__(16) float Bs[16][64];
  const int tid = threadIdx.x;
  const int bm = blockIdx.y * 64, bn = blockIdx.x * 64;
  const int row = tid >> 2;
  const int kq = (tid & 3) * 4;
  const int ty = tid >> 4, tx = tid & 15;
  float acc[4][4];
#pragma unroll
  for (int i = 0; i < 4; ++i)
#pragma unroll
    for (int j = 0; j < 4; ++j) acc[i][j] = 0.f;
  for (int kk = 0; kk < K; kk += 16) {
    float4 av = *(const float4*)&A[(size_t)(bm + row) * K + kk + kq];
    float4 bv = *(const float4*)&W[(size_t)(bn + row) * K + kk + kq];
    As[kq + 0][row] = av.x; As[kq + 1][row] = av.y;
    As[kq + 2][row] = av.z; As[kq + 3][row] = av.w;
    Bs[kq + 0][row] = bv.x; Bs[kq + 1][row] = bv.y;
    Bs[kq + 2][row] = bv.z; Bs[kq + 3][row] = bv.w;
    __syncthreads();
#pragma unroll
    for (int k = 0; k < 16; ++k) {
      float4 a = *(const float4*)&As[k][ty * 4];
      float4 b = *(const float4*)&Bs[k][tx * 4];
      acc[0][0] += a.x * b.x; acc[0][1] += a.x * b.y;
      acc[0][2] += a.x * b.z; acc[0][3] += a.x * b.w;
      acc[1][0] += a.y * b.x; acc[1][1] += a.y * b.y;
      acc[1][2] += a.y * b.z; acc[1][3] += a.y * b.w;
      acc[2][0] += a.z * b.x; acc[2][1] += a.z * b.y;
      acc[2][2] += a.z * b.z; acc[2][3] += a.z * b.w;
      acc[3][0] += a.w * b.x; acc[3][1] += a.w * b.y;
      acc[3][2] += a.w * b.z; acc[3][3] += a.w * b.w;
    }
    __syncthreads();
  }
  float4 bia = *(const float4*)&bias[bn + tx * 4];
#pragma unroll
  for (int i = 0; i < 4; ++i) {
    const int m = bm + ty * 4 + i;
    float4 v;
    v.x = acc[i][0] + bia.x; v.y = acc[i][1] + bia.y;
    v.z = acc[i][2] + bia.z; v.w = acc[i][3] + bia.w;
    if (relu) {
      v.x = fmaxf(v.x, 0.f); v.y = fmaxf(v.y, 0.f);
      v.z = fmaxf(v.z, 0.f); v.w = fmaxf(v.w, 0.f);
    }
    *(float4*)&C[(size_t)m * N + bn + tx * 4] = v;
  }
}

// fc3: one wave per row, N=10, K=512
__global__ __launch_bounds__(256) void k_fc3(const float* __restrict__ A,
                                             const float* __restrict__ W,
                                             const float* __restrict__ b,
                                             float* __restrict__ out) {
  const int wid = threadIdx.x >> 6, lane = threadIdx.x & 63;
  const int row = blockIdx.x * 4 + wid;
  float p[10];
#pragma unroll
  for (int o = 0; o < 10; ++o) p[o] = 0.f;
  const float* a = A + (size_t)row * 512;
#pragma unroll
  for (int jj = 0; jj < 8; ++jj) {
    const int j = lane + jj * 64;
    float av = a[j];
#pragma unroll
    for (int o = 0; o < 10; ++o) p[o] += av * W[o * 512 + j];
  }
#pragma unroll
  for (int o = 0; o < 10; ++o) p[o] = wave_sum(p[o]);
  if (lane == 0) {
#pragma unroll
    for (int o = 0; o < 10; ++o) out[(size_t)row * 10 + o] = p[o] + b[o];
  }
}

}  // namespace

extern "C" void kernel_launch(void* const* d_in, const int* in_sizes, int n_in,
                              void* d_out, int out_size, void* d_ws,
                              size_t ws_size, hipStream_t stream) {
  const float* x      = (const float*)d_in[0];
  const float* dfe1_w = (const float*)d_in[1];
  const float* dse1_g = (const float*)d_in[2];
  const float* dse1_b = (const float*)d_in[3];
  const float* dse1_w = (const float*)d_in[4];
  const float* bn1_g  = (const float*)d_in[5];
  const float* bn1_b  = (const float*)d_in[6];
  const float* dfe2_w = (const float*)d_in[7];
  const float* dse2_g = (const float*)d_in[8];
  const float* dse2_b = (const float*)d_in[9];
  const float* dse2_w = (const float*)d_in[10];
  const float* bn2_g  = (const float*)d_in[11];
  const float* bn2_b  = (const float*)d_in[12];
  const float* fc1_w  = (const float*)d_in[13];
  const float* fc1_b  = (const float*)d_in[14];
  const float* fc2_w  = (const float*)d_in[15];
  const float* fc2_b  = (const float*)d_in[16];
  const float* fc3_w  = (const float*)d_in[17];
  const float* fc3_b  = (const float*)d_in[18];
  float* out = (float*)d_out;
  char* ws = (char*)d_ws;
  float* h1 = (float*)(ws + OFF_H1);
  float* y2 = (float*)(ws + OFF_Y2);
  float* h2 = (float*)(ws + OFF_H2);
  float* a1 = (float*)(ws + OFF_A1);
  float* a2 = (float*)(ws + OFF_A2);
  double* st = (double*)(ws + OFF_ST);
  // stat slots (x8 doubles each): st1 @0(16), st2 @16(16), st3 @32(32), st4 @64(32)
  double* ST1 = st;
  double* ST2 = st + (size_t)16 * 8;
  double* ST3 = st + (size_t)32 * 8;
  double* ST4 = st + (size_t)64 * 8;

  hipMemsetAsync(st, 0, 96 * 8 * sizeof(double), stream);
  k_conv1_stats<<<512, 256, 0, stream>>>(x, dfe1_w, ST1);
  k_conv1_xr<<<512, 256, 0, stream>>>(x, dfe1_w, dse1_g, dse1_b, ST1, ST2);
  k_conv1_out<<<512, 256, 0, stream>>>(x, dfe1_w, dse1_g, dse1_b, dse1_w,
                                       bn1_g, bn1_b, ST1, ST2, h1);
  k_conv2_stats<<<512, 256, 0, stream>>>(h1, dfe2_w, y2, ST3);
  k_xr2_stats<<<4096, 256, 0, stream>>>(y2, dse2_g, dse2_b, ST3, ST4);
  k_l2_out<<<1024, 256, 0, stream>>>(y2, dse2_g, dse2_b, dse2_w, bn2_g, bn2_b,
                                     ST3, ST4, h2);
  k_fc_gemm<<<dim3(8, 64), 256, 0, stream>>>(h2, fc1_w, fc1_b, a1, 512, 2048, 1);
  k_fc_gemm<<<dim3(8, 64), 256, 0, stream>>>(a1, fc2_w, fc2_b, a2, 512, 512, 1);
  k_fc3<<<1024, 256, 0, stream>>>(a2, fc3_w, fc3_b, out);
}

// Round 3
// 529.676 us; speedup vs baseline: 1.6558x; 1.1900x over previous
//
#include <hip/hip_runtime.h>
#include <math.h>

#define EPS_BN 1e-5

namespace {

constexpr double CNT1 = 4096.0 * 1024.0;  // layer1 BN count: B*32*32
constexpr double CNT2 = 4096.0 * 256.0;   // layer2 BN count: B*16*16

// workspace layout (bytes). Required ws >= ~131 MiB.
constexpr size_t OFF_H1 = 0;            // [4096,16,16,16] f32 = 64 MiB
constexpr size_t OFF_Y2 = 67108864;     // [4096,16,16,16] f32 = 64 MiB
constexpr size_t OFF_H2 = 0;            // [4096,2048] bf16 (reuses h1 after conv2)
constexpr size_t OFF_A1 = 33554432;     // [4096,512] bf16
constexpr size_t OFF_A2 = 41943040;     // [4096,512] f32
constexpr size_t OFF_ST = 134217728;    // BN stats: 96 slots x 64B
constexpr size_t OFF_WB1 = 134283264;   // fc1_w bf16 [512,2048] = 2 MiB
constexpr size_t OFF_WB2 = 136380416;   // fc2_w bf16 [512,512] = 0.5 MiB

#define STG(p, i) (p)[(size_t)(i) * 8]

typedef short bf16x8 __attribute__((ext_vector_type(8)));
typedef float f32x4 __attribute__((ext_vector_type(4)));

__device__ __forceinline__ short f2bf(float f) {
  unsigned u = __float_as_uint(f);
  u = (u + 0x7fffu + ((u >> 16) & 1u)) >> 16;
  return (short)u;
}

__device__ __forceinline__ float wave_sum(float v) {
#pragma unroll
  for (int o = 32; o > 0; o >>= 1) v += __shfl_down(v, o, 64);
  return v;
}

template <int NV>
__device__ __forceinline__ void block_stats_atomic(const float* s, const float* q,
                                                   double* __restrict__ st) {
  __shared__ float red[4][NV * 2];
  const int lane = threadIdx.x & 63, wid = threadIdx.x >> 6;
#pragma unroll
  for (int c = 0; c < NV; ++c) {
    float sv = wave_sum(s[c]);
    float qv = wave_sum(q[c]);
    if (lane == 0) { red[wid][2 * c] = sv; red[wid][2 * c + 1] = qv; }
  }
  __syncthreads();
  if (threadIdx.x < NV * 2) {
    float v = red[0][threadIdx.x] + red[1][threadIdx.x] + red[2][threadIdx.x] +
              red[3][threadIdx.x];
    unsafeAtomicAdd(st + (size_t)threadIdx.x * 8, (double)v);
  }
}

// ---------------- layer 1: conv 3x3, 3->8, on 32x32, pad 1 -------------------
__device__ __forceinline__ void conv1_stage_img(const float* __restrict__ xp,
                                                float* xs, int tid) {
  for (int i = tid; i < 3072; i += 256) {
    int ci = i >> 10, r = (i >> 5) & 31, c = i & 31;
    xs[ci * 1156 + (r + 1) * 34 + (c + 1)] = xp[i];
  }
}

__device__ __forceinline__ void conv1_compute_rows(const float* xs,
                                                   const float* wk, int tx,
                                                   int ty, float acc[4][8]) {
#pragma unroll
  for (int p = 0; p < 4; ++p)
#pragma unroll
    for (int co = 0; co < 8; ++co) acc[p][co] = 0.f;
#pragma unroll
  for (int ci = 0; ci < 3; ++ci)
#pragma unroll
    for (int dy = 0; dy < 3; ++dy)
#pragma unroll
      for (int dx = 0; dx < 3; ++dx) {
        const int j = ci * 9 + dy * 3 + dx;
        float wv[8];
        *(float4*)&wv[0] = *(const float4*)&wk[j * 8];
        *(float4*)&wv[4] = *(const float4*)&wk[j * 8 + 4];
#pragma unroll
        for (int p = 0; p < 4; ++p) {
          float xv = xs[ci * 1156 + (ty + 8 * p + dy) * 34 + (tx + dx)];
#pragma unroll
          for (int co = 0; co < 8; ++co) acc[p][co] += xv * wv[co];
        }
      }
}

__device__ __forceinline__ void conv1_compute_quad(const float* xs,
                                                   const float* wk, int tx,
                                                   int ty, float acc[4][8]) {
#pragma unroll
  for (int p = 0; p < 4; ++p)
#pragma unroll
    for (int co = 0; co < 8; ++co) acc[p][co] = 0.f;
#pragma unroll
  for (int ci = 0; ci < 3; ++ci)
#pragma unroll
    for (int dy = 0; dy < 3; ++dy)
#pragma unroll
      for (int dx = 0; dx < 3; ++dx) {
        const int j = ci * 9 + dy * 3 + dx;
        float wv[8];
        *(float4*)&wv[0] = *(const float4*)&wk[j * 8];
        *(float4*)&wv[4] = *(const float4*)&wk[j * 8 + 4];
#pragma unroll
        for (int p = 0; p < 4; ++p) {
          const int pr = p >> 1, pc = p & 1;
          float xv = xs[ci * 1156 + (2 * ty + pr + dy) * 34 + (2 * tx + pc + dx)];
#pragma unroll
          for (int co = 0; co < 8; ++co) acc[p][co] += xv * wv[co];
        }
      }
}

__global__ __launch_bounds__(256) void k_conv1_stats(
    const float* __restrict__ x, const float* __restrict__ w1,
    double* __restrict__ st1) {
  __shared__ __align__(16) float xs[3 * 34 * 34];
  __shared__ __align__(16) float wk[216];
  const int tid = threadIdx.x;
  for (int i = tid; i < 3 * 34 * 34; i += 256) xs[i] = 0.f;
  if (tid < 216) wk[(tid % 27) * 8 + tid / 27] = w1[tid];
  const int tx = tid & 31, ty = tid >> 5;
  float s[8], q[8];
#pragma unroll
  for (int c = 0; c < 8; ++c) { s[c] = 0.f; q[c] = 0.f; }
  for (int img = 0; img < 8; ++img) {
    __syncthreads();
    conv1_stage_img(x + ((size_t)blockIdx.x * 8 + img) * 3072, xs, tid);
    __syncthreads();
    float acc[4][8];
    conv1_compute_rows(xs, wk, tx, ty, acc);
#pragma unroll
    for (int co = 0; co < 8; ++co)
#pragma unroll
      for (int p = 0; p < 4; ++p) {
        float v = acc[p][co];
        s[co] += v; q[co] += v * v;
      }
  }
  block_stats_atomic<8>(s, q, st1);
}

__global__ __launch_bounds__(256) void k_conv1_xr(
    const float* __restrict__ x, const float* __restrict__ w1,
    const float* __restrict__ g1, const float* __restrict__ b1,
    const double* __restrict__ st1, double* __restrict__ st2) {
  __shared__ __align__(16) float xs[3 * 34 * 34];
  __shared__ __align__(16) float wk[216];
  const int tid = threadIdx.x;
  for (int i = tid; i < 3 * 34 * 34; i += 256) xs[i] = 0.f;
  if (tid < 216) wk[(tid % 27) * 8 + tid / 27] = w1[tid];
  float a1[8], c1[8];
#pragma unroll
  for (int co = 0; co < 8; ++co) {
    double sd = STG(st1, 2 * co), qd = STG(st1, 2 * co + 1);
    double md = sd / CNT1;
    float inv1 = (float)(1.0 / sqrt(qd / CNT1 - md * md + (double)EPS_BN));
    a1[co] = inv1 * g1[co];
    c1[co] = b1[co] - (float)md * a1[co];
  }
  const int tx = tid & 31, ty = tid >> 5;
  float s[8], q[8];
#pragma unroll
  for (int c = 0; c < 8; ++c) { s[c] = 0.f; q[c] = 0.f; }
  for (int img = 0; img < 8; ++img) {
    __syncthreads();
    conv1_stage_img(x + ((size_t)blockIdx.x * 8 + img) * 3072, xs, tid);
    __syncthreads();
    float acc[4][8];
    conv1_compute_rows(xs, wk, tx, ty, acc);
#pragma unroll
    for (int co = 0; co < 8; ++co)
#pragma unroll
      for (int p = 0; p < 4; ++p) {
        float xr = fmaxf(acc[p][co] * a1[co] + c1[co], 0.f);
        s[co] += xr; q[co] += xr * xr;
      }
  }
  block_stats_atomic<8>(s, q, st2);
}

__global__ __launch_bounds__(256) void k_conv1_out(
    const float* __restrict__ x, const float* __restrict__ w1,
    const float* __restrict__ g1, const float* __restrict__ b1,
    const float* __restrict__ dsew, const float* __restrict__ bng,
    const float* __restrict__ bnb, const double* __restrict__ st1,
    const double* __restrict__ st2, float* __restrict__ h1) {
  __shared__ __align__(16) float xs[3 * 34 * 34];
  __shared__ __align__(16) float wk[216];
  __shared__ float cA1[8], cC1[8], cS2[16], cO2[16];
  const int tid = threadIdx.x;
  for (int i = tid; i < 3 * 34 * 34; i += 256) xs[i] = 0.f;
  if (tid < 216) wk[(tid % 27) * 8 + tid / 27] = w1[tid];
  if (tid < 16) {
    const int i = tid >> 1, g = tid & 1;
    double sd = STG(st1, 2 * i), qd = STG(st1, 2 * i + 1);
    double md = sd / CNT1;
    float inv1 = (float)(1.0 / sqrt(qd / CNT1 - md * md + (double)EPS_BN));
    float a1 = inv1 * g1[i];
    if (g == 0) { cA1[i] = a1; cC1[i] = b1[i] - (float)md * a1; }
    double s2 = STG(st2, 2 * i), q2 = STG(st2, 2 * i + 1);
    double mx = s2 / CNT1, vx = q2 / CNT1 - mx * mx;
    float w = dsew[i * 2 + g];
    double inv2 = 1.0 / sqrt((double)w * w * vx + (double)EPS_BN);
    cS2[tid] = (float)(w * inv2) * bng[tid];
    cO2[tid] = bnb[tid] - (float)(w * mx * inv2) * bng[tid];
  }
  const int tx = tid & 15, ty = tid >> 4;
  for (int img = 0; img < 8; ++img) {
    const int n = blockIdx.x * 8 + img;
    __syncthreads();
    conv1_stage_img(x + (size_t)n * 3072, xs, tid);
    __syncthreads();
    float acc[4][8];
    conv1_compute_quad(xs, wk, tx, ty, acc);
#pragma unroll
    for (int i = 0; i < 8; ++i) {
      float xr[4];
#pragma unroll
      for (int p = 0; p < 4; ++p)
        xr[p] = fmaxf(acc[p][i] * cA1[i] + cC1[i], 0.f);
#pragma unroll
      for (int g = 0; g < 2; ++g) {
        const int c = 2 * i + g;
        float sc = cS2[c], of = cO2[c];
        float r0 = fmaxf(xr[0] * sc + of, 0.f);
        float r1 = fmaxf(xr[1] * sc + of, 0.f);
        float r2 = fmaxf(xr[2] * sc + of, 0.f);
        float r3 = fmaxf(xr[3] * sc + of, 0.f);
        h1[(size_t)(n * 16 + c) * 256 + ty * 16 + tx] =
            fmaxf(fmaxf(r0, r1), fmaxf(r2, r3));
      }
    }
  }
}

// ---------------- layer 2: conv 3x3, 16->16, on 16x16, pad 1 -----------------
__global__ __launch_bounds__(256) void k_conv2_stats(
    const float* __restrict__ h1, const float* __restrict__ w2,
    float* __restrict__ y2, double* __restrict__ st3) {
  __shared__ __align__(16) float hs[2][16 * 18 * 18];
  __shared__ __align__(16) float wt[2304];  // [ci][k][co], co contiguous
  const int tid = threadIdx.x;
  for (int i = tid; i < 2 * 5184; i += 256) (&hs[0][0])[i] = 0.f;
  for (int i = tid; i < 2304; i += 256) {
    int co = i & 15, r = i >> 4, ci = r / 9, k = r % 9;
    wt[i] = w2[(co * 16 + ci) * 9 + k];
  }
  const int tx = tid & 15, ty = tid >> 4;
  float s[16], q[16];
#pragma unroll
  for (int c = 0; c < 16; ++c) { s[c] = 0.f; q[c] = 0.f; }
  for (int it = 0; it < 4; ++it) {
    const int n0 = blockIdx.x * 8 + it * 2;
    __syncthreads();
#pragma unroll
    for (int img = 0; img < 2; ++img) {
      const float* hp = h1 + (size_t)(n0 + img) * 4096;
      for (int i = tid; i < 4096; i += 256) {
        int ci = i >> 8, r = (i >> 4) & 15, c = i & 15;
        hs[img][ci * 324 + (r + 1) * 18 + (c + 1)] = hp[i];
      }
    }
    __syncthreads();
    float acc[2][16];
#pragma unroll
    for (int img = 0; img < 2; ++img)
#pragma unroll
      for (int co = 0; co < 16; ++co) acc[img][co] = 0.f;
    for (int ci = 0; ci < 16; ++ci) {
#pragma unroll
      for (int k = 0; k < 9; ++k) {
        const int dy = k / 3, dx = k % 3;
        float wv[16];
        const float4* wp = (const float4*)&wt[(ci * 9 + k) * 16];
        *(float4*)&wv[0] = wp[0];
        *(float4*)&wv[4] = wp[1];
        *(float4*)&wv[8] = wp[2];
        *(float4*)&wv[12] = wp[3];
        float xa = hs[0][ci * 324 + (ty + dy) * 18 + (tx + dx)];
        float xb = hs[1][ci * 324 + (ty + dy) * 18 + (tx + dx)];
#pragma unroll
        for (int co = 0; co < 16; ++co) {
          acc[0][co] += xa * wv[co];
          acc[1][co] += xb * wv[co];
        }
      }
    }
#pragma unroll
    for (int co = 0; co < 16; ++co) {
      float va = acc[0][co], vb = acc[1][co];
      y2[(size_t)(n0 * 16 + co) * 256 + tid] = va;
      y2[(size_t)((n0 + 1) * 16 + co) * 256 + tid] = vb;
      s[co] += va + vb; q[co] += va * va + vb * vb;
    }
  }
  block_stats_atomic<16>(s, q, st3);
}

__global__ __launch_bounds__(256) void k_xr2_stats(
    const float* __restrict__ y2, const float* __restrict__ g2,
    const float* __restrict__ b2, const double* __restrict__ st3,
    double* __restrict__ st4) {
  const int c = blockIdx.x & 15, n0 = (blockIdx.x >> 4) << 4;
  double sd = STG(st3, 2 * c), qd = STG(st3, 2 * c + 1);
  double md = sd / CNT2;
  float m = (float)md;
  float inv = (float)(1.0 / sqrt(qd / CNT2 - md * md + (double)EPS_BN));
  float gg = g2[c], bb = b2[c];
  float s = 0.f, q = 0.f;
#pragma unroll
  for (int k = 0; k < 16; ++k) {
    float v = y2[((size_t)(n0 + k) * 16 + c) * 256 + threadIdx.x];
    float xr = fmaxf((v - m) * inv * gg + bb, 0.f);
    s += xr; q += xr * xr;
  }
  block_stats_atomic<1>(&s, &q, st4 + (size_t)(2 * c) * 8);
}

// y2 -> BN+relu -> scale-expand -> BN+relu -> 2x2 maxpool -> h2 bf16 [4096,2048]
__global__ __launch_bounds__(256) void k_l2_out(
    const float* __restrict__ y2, const float* __restrict__ g2,
    const float* __restrict__ b2, const float* __restrict__ dsew,
    const float* __restrict__ bng, const float* __restrict__ bnb,
    const double* __restrict__ st3, const double* __restrict__ st4,
    short* __restrict__ h2) {
  __shared__ float cS3[16], cO3[16], cS4[32], cO4[32];
  const int tid = threadIdx.x;
  if (tid < 32) {
    const int i = tid >> 1, g = tid & 1;
    double sd = STG(st3, 2 * i), qd = STG(st3, 2 * i + 1);
    double md = sd / CNT2;
    float inv3 = (float)(1.0 / sqrt(qd / CNT2 - md * md + (double)EPS_BN));
    float a3 = inv3 * g2[i];
    if (g == 0) { cS3[i] = a3; cO3[i] = b2[i] - (float)md * a3; }
    double s4 = STG(st4, 2 * i), q4 = STG(st4, 2 * i + 1);
    double mx = s4 / CNT2, vx = q4 / CNT2 - mx * mx;
    float w = dsew[2 * i + g];
    double inv4 = 1.0 / sqrt((double)w * w * vx + (double)EPS_BN);
    cS4[tid] = (float)(w * inv4) * bng[tid];
    cO4[tid] = bnb[tid] - (float)(w * mx * inv4) * bng[tid];
  }
  __syncthreads();
  const int sub = tid >> 6, lane = tid & 63;
  const int n = blockIdx.x * 4 + sub;
  const int px = lane & 7, py = lane >> 3;
#pragma unroll
  for (int i = 0; i < 16; ++i) {
    const size_t base = ((size_t)n * 16 + i) * 256;
    float2 v01 = *(const float2*)&y2[base + (2 * py) * 16 + 2 * px];
    float2 v23 = *(const float2*)&y2[base + (2 * py + 1) * 16 + 2 * px];
    float a3 = cS3[i], c3 = cO3[i];
    float xr0 = fmaxf(v01.x * a3 + c3, 0.f);
    float xr1 = fmaxf(v01.y * a3 + c3, 0.f);
    float xr2 = fmaxf(v23.x * a3 + c3, 0.f);
    float xr3 = fmaxf(v23.y * a3 + c3, 0.f);
#pragma unroll
    for (int g = 0; g < 2; ++g) {
      const int c = 2 * i + g;
      float sc = cS4[c], of = cO4[c];
      float r0 = fmaxf(xr0 * sc + of, 0.f);
      float r1 = fmaxf(xr1 * sc + of, 0.f);
      float r2 = fmaxf(xr2 * sc + of, 0.f);
      float r3 = fmaxf(xr3 * sc + of, 0.f);
      h2[(size_t)n * 2048 + c * 64 + py * 8 + px] =
          f2bf(fmaxf(fmaxf(r0, r1), fmaxf(r2, r3)));
    }
  }
}

// cast fc1_w (512x2048) and fc2_w (512x512) to bf16
__global__ __launch_bounds__(256) void k_cast_w(const float* __restrict__ w1,
                                                const float* __restrict__ w2,
                                                short* __restrict__ o1,
                                                short* __restrict__ o2) {
  const int i = blockIdx.x * 256 + threadIdx.x;
  if (i < 1048576) o1[i] = f2bf(w1[i]);
  else o2[i - 1048576] = f2bf(w2[i - 1048576]);
}

// ------------- FC via MFMA: C[M,512] = act(A[M,K]bf16 @ W[512,K]bf16^T + b) --
// LDS-free: A/W are K-major so MFMA fragments are direct contiguous 16B loads.
// Block = 64 rows x 64 cols; 4 waves split N (16 cols each); per wave k-step:
// 4 a-frags + 1 b-frag + 4 MFMAs.
template <int K, int RELU, int OUT_BF16>
__global__ __launch_bounds__(256) void k_fc_mfma(
    const short* __restrict__ A, const short* __restrict__ W,
    const float* __restrict__ bias, void* __restrict__ Cv) {
  const int wv = threadIdx.x >> 6, lane = threadIdx.x & 63;
  const int bm = blockIdx.y * 64;
  const int bn = blockIdx.x * 64 + wv * 16;
  const int cl = lane & 15, quad = lane >> 4;
  const short* ap = A + (size_t)(bm + cl) * K + quad * 8;
  const short* bp = W + (size_t)(bn + cl) * K + quad * 8;
  f32x4 acc0 = {0.f, 0.f, 0.f, 0.f}, acc1 = acc0, acc2 = acc0, acc3 = acc0;
#pragma unroll 4
  for (int k0 = 0; k0 < K; k0 += 32) {
    bf16x8 b = *(const bf16x8*)bp;
    bf16x8 a0 = *(const bf16x8*)ap;
    bf16x8 a1 = *(const bf16x8*)(ap + (size_t)16 * K);
    bf16x8 a2 = *(const bf16x8*)(ap + (size_t)32 * K);
    bf16x8 a3 = *(const bf16x8*)(ap + (size_t)48 * K);
    ap += 32; bp += 32;
    acc0 = __builtin_amdgcn_mfma_f32_16x16x32_bf16(a0, b, acc0, 0, 0, 0);
    acc1 = __builtin_amdgcn_mfma_f32_16x16x32_bf16(a1, b, acc1, 0, 0, 0);
    acc2 = __builtin_amdgcn_mfma_f32_16x16x32_bf16(a2, b, acc2, 0, 0, 0);
    acc3 = __builtin_amdgcn_mfma_f32_16x16x32_bf16(a3, b, acc3, 0, 0, 0);
  }
  const float bia = bias[bn + cl];
  f32x4 av[4] = {acc0, acc1, acc2, acc3};
#pragma unroll
  for (int rt = 0; rt < 4; ++rt) {
#pragma unroll
    for (int r = 0; r < 4; ++r) {
      const int row = bm + rt * 16 + quad * 4 + r;
      float v = av[rt][r] + bia;
      if (RELU) v = fmaxf(v, 0.f);
      if (OUT_BF16)
        ((short*)Cv)[(size_t)row * 512 + bn + cl] = f2bf(v);
      else
        ((float*)Cv)[(size_t)row * 512 + bn + cl] = v;
    }
  }
}

// fc3: one wave per row, N=10, K=512, fp32
__global__ __launch_bounds__(256) void k_fc3(const float* __restrict__ A,
                                             const float* __restrict__ W,
                                             const float* __restrict__ b,
                                             float* __restrict__ out) {
  const int wid = threadIdx.x >> 6, lane = threadIdx.x & 63;
  const int row = blockIdx.x * 4 + wid;
  float p[10];
#pragma unroll
  for (int o = 0; o < 10; ++o) p[o] = 0.f;
  const float* a = A + (size_t)row * 512;
#pragma unroll
  for (int jj = 0; jj < 8; ++jj) {
    const int j = lane + jj * 64;
    float av = a[j];
#pragma unroll
    for (int o = 0; o < 10; ++o) p[o] += av * W[o * 512 + j];
  }
#pragma unroll
  for (int o = 0; o < 10; ++o) p[o] = wave_sum(p[o]);
  if (lane == 0) {
#pragma unroll
    for (int o = 0; o < 10; ++o) out[(size_t)row * 10 + o] = p[o] + b[o];
  }
}

}  // namespace

extern "C" void kernel_launch(void* const* d_in, const int* in_sizes, int n_in,
                              void* d_out, int out_size, void* d_ws,
                              size_t ws_size, hipStream_t stream) {
  const float* x      = (const float*)d_in[0];
  const float* dfe1_w = (const float*)d_in[1];
  const float* dse1_g = (const float*)d_in[2];
  const float* dse1_b = (const float*)d_in[3];
  const float* dse1_w = (const float*)d_in[4];
  const float* bn1_g  = (const float*)d_in[5];
  const float* bn1_b  = (const float*)d_in[6];
  const float* dfe2_w = (const float*)d_in[7];
  const float* dse2_g = (const float*)d_in[8];
  const float* dse2_b = (const float*)d_in[9];
  const float* dse2_w = (const float*)d_in[10];
  const float* bn2_g  = (const float*)d_in[11];
  const float* bn2_b  = (const float*)d_in[12];
  const float* fc1_w  = (const float*)d_in[13];
  const float* fc1_b  = (const float*)d_in[14];
  const float* fc2_w  = (const float*)d_in[15];
  const float* fc2_b  = (const float*)d_in[16];
  const float* fc3_w  = (const float*)d_in[17];
  const float* fc3_b  = (const float*)d_in[18];
  float* out = (float*)d_out;
  char* ws = (char*)d_ws;
  float* h1 = (float*)(ws + OFF_H1);
  float* y2 = (float*)(ws + OFF_Y2);
  short* h2 = (short*)(ws + OFF_H2);
  short* a1 = (short*)(ws + OFF_A1);
  float* a2 = (float*)(ws + OFF_A2);
  short* wb1 = (short*)(ws + OFF_WB1);
  short* wb2 = (short*)(ws + OFF_WB2);
  double* st = (double*)(ws + OFF_ST);
  double* ST1 = st;
  double* ST2 = st + (size_t)16 * 8;
  double* ST3 = st + (size_t)32 * 8;
  double* ST4 = st + (size_t)64 * 8;

  hipMemsetAsync(st, 0, 96 * 8 * sizeof(double), stream);
  k_cast_w<<<5120, 256, 0, stream>>>(fc1_w, fc2_w, wb1, wb2);
  k_conv1_stats<<<512, 256, 0, stream>>>(x, dfe1_w, ST1);
  k_conv1_xr<<<512, 256, 0, stream>>>(x, dfe1_w, dse1_g, dse1_b, ST1, ST2);
  k_conv1_out<<<512, 256, 0, stream>>>(x, dfe1_w, dse1_g, dse1_b, dse1_w,
                                       bn1_g, bn1_b, ST1, ST2, h1);
  k_conv2_stats<<<512, 256, 0, stream>>>(h1, dfe2_w, y2, ST3);
  k_xr2_stats<<<4096, 256, 0, stream>>>(y2, dse2_g, dse2_b, ST3, ST4);
  k_l2_out<<<1024, 256, 0, stream>>>(y2, dse2_g, dse2_b, dse2_w, bn2_g, bn2_b,
                                     ST3, ST4, h2);
  k_fc_mfma<2048, 1, 1><<<dim3(8, 64), 256, 0, stream>>>(h2, wb1, fc1_b, a1);
  k_fc_mfma<512, 1, 0><<<dim3(8, 64), 256, 0, stream>>>(a1, wb2, fc2_b, a2);
  k_fc3<<<1024, 256, 0, stream>>>(a2, fc3_w, fc3_b, out);
}

// Round 4
// 461.789 us; speedup vs baseline: 1.8992x; 1.1470x over previous
//
#include <hip/hip_runtime.h>
#include <math.h>

#define EPS_BN 1e-5

namespace {

constexpr double CNT1 = 4096.0 * 1024.0;  // layer1 BN count: B*32*32
constexpr double CNT2 = 4096.0 * 256.0;   // layer2 BN count: B*16*16

// workspace layout (bytes). Required ws >= ~137 MiB.
constexpr size_t OFF_H1 = 0;            // [4096,256px,16ci] bf16 = 32 MiB
constexpr size_t OFF_Y2 = 67108864;     // [4096,16,16,16] f32 = 64 MiB
constexpr size_t OFF_H2 = 0;            // [4096,2048] bf16 (reuses h1 after conv2)
constexpr size_t OFF_A1 = 33554432;     // [4096,512] bf16
constexpr size_t OFF_A2 = 41943040;     // [4096,512] f32
constexpr size_t OFF_ST = 134217728;    // BN stats: 96 slots x 64B
constexpr size_t OFF_WB1 = 134283264;   // fc1_w bf16 [512,2048] = 2 MiB
constexpr size_t OFF_WB2 = 136380416;   // fc2_w bf16 [512,512] = 0.5 MiB

#define STG(p, i) (p)[(size_t)(i) * 8]

typedef short bf16x8 __attribute__((ext_vector_type(8)));
typedef float f32x4 __attribute__((ext_vector_type(4)));

__device__ __forceinline__ short f2bf(float f) {
  unsigned u = __float_as_uint(f);
  u = (u + 0x7fffu + ((u >> 16) & 1u)) >> 16;
  return (short)u;
}

__device__ __forceinline__ float wave_sum(float v) {
#pragma unroll
  for (int o = 32; o > 0; o >>= 1) v += __shfl_down(v, o, 64);
  return v;
}

template <int NV>
__device__ __forceinline__ void block_stats_atomic(const float* s, const float* q,
                                                   double* __restrict__ st) {
  __shared__ float red[4][NV * 2];
  const int lane = threadIdx.x & 63, wid = threadIdx.x >> 6;
#pragma unroll
  for (int c = 0; c < NV; ++c) {
    float sv = wave_sum(s[c]);
    float qv = wave_sum(q[c]);
    if (lane == 0) { red[wid][2 * c] = sv; red[wid][2 * c + 1] = qv; }
  }
  __syncthreads();
  if (threadIdx.x < NV * 2) {
    float v = red[0][threadIdx.x] + red[1][threadIdx.x] + red[2][threadIdx.x] +
              red[3][threadIdx.x];
    unsafeAtomicAdd(st + (size_t)threadIdx.x * 8, (double)v);
  }
}

// ---------------- layer 1: conv 3x3, 3->8, on 32x32, pad 1 -------------------
__device__ __forceinline__ void conv1_stage_img(const float* __restrict__ xp,
                                                float* xs, int tid) {
  for (int i = tid; i < 3072; i += 256) {
    int ci = i >> 10, r = (i >> 5) & 31, c = i & 31;
    xs[ci * 1156 + (r + 1) * 34 + (c + 1)] = xp[i];
  }
}

__device__ __forceinline__ void conv1_compute_rows(const float* xs,
                                                   const float* wk, int tx,
                                                   int ty, float acc[4][8]) {
#pragma unroll
  for (int p = 0; p < 4; ++p)
#pragma unroll
    for (int co = 0; co < 8; ++co) acc[p][co] = 0.f;
#pragma unroll
  for (int ci = 0; ci < 3; ++ci)
#pragma unroll
    for (int dy = 0; dy < 3; ++dy)
#pragma unroll
      for (int dx = 0; dx < 3; ++dx) {
        const int j = ci * 9 + dy * 3 + dx;
        float wv[8];
        *(float4*)&wv[0] = *(const float4*)&wk[j * 8];
        *(float4*)&wv[4] = *(const float4*)&wk[j * 8 + 4];
#pragma unroll
        for (int p = 0; p < 4; ++p) {
          float xv = xs[ci * 1156 + (ty + 8 * p + dy) * 34 + (tx + dx)];
#pragma unroll
          for (int co = 0; co < 8; ++co) acc[p][co] += xv * wv[co];
        }
      }
}

__device__ __forceinline__ void conv1_compute_quad(const float* xs,
                                                   const float* wk, int tx,
                                                   int ty, float acc[4][8]) {
#pragma unroll
  for (int p = 0; p < 4; ++p)
#pragma unroll
    for (int co = 0; co < 8; ++co) acc[p][co] = 0.f;
#pragma unroll
  for (int ci = 0; ci < 3; ++ci)
#pragma unroll
    for (int dy = 0; dy < 3; ++dy)
#pragma unroll
      for (int dx = 0; dx < 3; ++dx) {
        const int j = ci * 9 + dy * 3 + dx;
        float wv[8];
        *(float4*)&wv[0] = *(const float4*)&wk[j * 8];
        *(float4*)&wv[4] = *(const float4*)&wk[j * 8 + 4];
#pragma unroll
        for (int p = 0; p < 4; ++p) {
          const int pr = p >> 1, pc = p & 1;
          float xv = xs[ci * 1156 + (2 * ty + pr + dy) * 34 + (2 * tx + pc + dx)];
#pragma unroll
          for (int co = 0; co < 8; ++co) acc[p][co] += xv * wv[co];
        }
      }
}

__global__ __launch_bounds__(256) void k_conv1_stats(
    const float* __restrict__ x, const float* __restrict__ w1,
    double* __restrict__ st1) {
  __shared__ __align__(16) float xs[3 * 34 * 34];
  __shared__ __align__(16) float wk[216];
  const int tid = threadIdx.x;
  for (int i = tid; i < 3 * 34 * 34; i += 256) xs[i] = 0.f;
  if (tid < 216) wk[(tid % 27) * 8 + tid / 27] = w1[tid];
  const int tx = tid & 31, ty = tid >> 5;
  float s[8], q[8];
#pragma unroll
  for (int c = 0; c < 8; ++c) { s[c] = 0.f; q[c] = 0.f; }
  for (int img = 0; img < 8; ++img) {
    __syncthreads();
    conv1_stage_img(x + ((size_t)blockIdx.x * 8 + img) * 3072, xs, tid);
    __syncthreads();
    float acc[4][8];
    conv1_compute_rows(xs, wk, tx, ty, acc);
#pragma unroll
    for (int co = 0; co < 8; ++co)
#pragma unroll
      for (int p = 0; p < 4; ++p) {
        float v = acc[p][co];
        s[co] += v; q[co] += v * v;
      }
  }
  block_stats_atomic<8>(s, q, st1);
}

__global__ __launch_bounds__(256) void k_conv1_xr(
    const float* __restrict__ x, const float* __restrict__ w1,
    const float* __restrict__ g1, const float* __restrict__ b1,
    const double* __restrict__ st1, double* __restrict__ st2) {
  __shared__ __align__(16) float xs[3 * 34 * 34];
  __shared__ __align__(16) float wk[216];
  const int tid = threadIdx.x;
  for (int i = tid; i < 3 * 34 * 34; i += 256) xs[i] = 0.f;
  if (tid < 216) wk[(tid % 27) * 8 + tid / 27] = w1[tid];
  float a1[8], c1[8];
#pragma unroll
  for (int co = 0; co < 8; ++co) {
    double sd = STG(st1, 2 * co), qd = STG(st1, 2 * co + 1);
    double md = sd / CNT1;
    float inv1 = (float)(1.0 / sqrt(qd / CNT1 - md * md + (double)EPS_BN));
    a1[co] = inv1 * g1[co];
    c1[co] = b1[co] - (float)md * a1[co];
  }
  const int tx = tid & 31, ty = tid >> 5;
  float s[8], q[8];
#pragma unroll
  for (int c = 0; c < 8; ++c) { s[c] = 0.f; q[c] = 0.f; }
  for (int img = 0; img < 8; ++img) {
    __syncthreads();
    conv1_stage_img(x + ((size_t)blockIdx.x * 8 + img) * 3072, xs, tid);
    __syncthreads();
    float acc[4][8];
    conv1_compute_rows(xs, wk, tx, ty, acc);
#pragma unroll
    for (int co = 0; co < 8; ++co)
#pragma unroll
      for (int p = 0; p < 4; ++p) {
        float xr = fmaxf(acc[p][co] * a1[co] + c1[co], 0.f);
        s[co] += xr; q[co] += xr * xr;
      }
  }
  block_stats_atomic<8>(s, q, st2);
}

// conv1 + BN1 + relu + scale-expand + BN2 + relu + 2x2 maxpool
// -> h1 bf16 NHWC [img][256px][16ci]
__global__ __launch_bounds__(256) void k_conv1_out(
    const float* __restrict__ x, const float* __restrict__ w1,
    const float* __restrict__ g1, const float* __restrict__ b1,
    const float* __restrict__ dsew, const float* __restrict__ bng,
    const float* __restrict__ bnb, const double* __restrict__ st1,
    const double* __restrict__ st2, short* __restrict__ h1) {
  __shared__ __align__(16) float xs[3 * 34 * 34];
  __shared__ __align__(16) float wk[216];
  __shared__ float cA1[8], cC1[8], cS2[16], cO2[16];
  const int tid = threadIdx.x;
  for (int i = tid; i < 3 * 34 * 34; i += 256) xs[i] = 0.f;
  if (tid < 216) wk[(tid % 27) * 8 + tid / 27] = w1[tid];
  if (tid < 16) {
    const int i = tid >> 1, g = tid & 1;
    double sd = STG(st1, 2 * i), qd = STG(st1, 2 * i + 1);
    double md = sd / CNT1;
    float inv1 = (float)(1.0 / sqrt(qd / CNT1 - md * md + (double)EPS_BN));
    float a1 = inv1 * g1[i];
    if (g == 0) { cA1[i] = a1; cC1[i] = b1[i] - (float)md * a1; }
    double s2 = STG(st2, 2 * i), q2 = STG(st2, 2 * i + 1);
    double mx = s2 / CNT1, vx = q2 / CNT1 - mx * mx;
    float w = dsew[i * 2 + g];
    double inv2 = 1.0 / sqrt((double)w * w * vx + (double)EPS_BN);
    cS2[tid] = (float)(w * inv2) * bng[tid];
    cO2[tid] = bnb[tid] - (float)(w * mx * inv2) * bng[tid];
  }
  const int tx = tid & 15, ty = tid >> 4;
  for (int img = 0; img < 8; ++img) {
    const int n = blockIdx.x * 8 + img;
    __syncthreads();
    conv1_stage_img(x + (size_t)n * 3072, xs, tid);
    __syncthreads();
    float acc[4][8];
    conv1_compute_quad(xs, wk, tx, ty, acc);
    short hv[16];
#pragma unroll
    for (int i = 0; i < 8; ++i) {
      float xr[4];
#pragma unroll
      for (int p = 0; p < 4; ++p)
        xr[p] = fmaxf(acc[p][i] * cA1[i] + cC1[i], 0.f);
#pragma unroll
      for (int g = 0; g < 2; ++g) {
        const int c = 2 * i + g;
        float sc = cS2[c], of = cO2[c];
        float r0 = fmaxf(xr[0] * sc + of, 0.f);
        float r1 = fmaxf(xr[1] * sc + of, 0.f);
        float r2 = fmaxf(xr[2] * sc + of, 0.f);
        float r3 = fmaxf(xr[3] * sc + of, 0.f);
        hv[c] = f2bf(fmaxf(fmaxf(r0, r1), fmaxf(r2, r3)));
      }
    }
    uint4* dst = (uint4*)&h1[((size_t)n * 256 + ty * 16 + tx) * 16];
    dst[0] = ((uint4*)hv)[0];
    dst[1] = ((uint4*)hv)[1];
  }
}

// ---------------- layer 2 conv via MFMA ---------------------------------
// 3x3 conv 16->16 as 9 shifted 1x1 convs, 2 shifts packed per K=32 MFMA.
// Per image row: M=16 pixel-cols, N=16 co, 5 MFMAs (10th shift slot zeroed).
// h1 bf16 NHWC staged zero-padded [18][18][16ci]; wt[10][co][ci] bf16.
// Block = 4 waves = 4 images/iter, 2 iters. Writes y2 fp32 + stats atomics.
__global__ __launch_bounds__(256) void k_conv2_mfma(
    const short* __restrict__ h1, const float* __restrict__ w2,
    float* __restrict__ y2, double* __restrict__ st3) {
  __shared__ short smem[4 * 5184 + 10 * 256];
  __shared__ float red[4][32];
  short* hs = smem;                 // 4 padded images
  short* wt = smem + 4 * 5184;      // [10][16co][16ci], slot 9 stays zero
  const int tid = threadIdx.x, wid = tid >> 6, lane = tid & 63;
  for (int i = tid; i < (4 * 5184 + 10 * 256) / 2; i += 256) ((int*)smem)[i] = 0;
  __syncthreads();
  for (int i = tid; i < 2304; i += 256) {
    const int s = i >> 8, co = (i >> 4) & 15, ci = i & 15;
    wt[i] = f2bf(w2[(co * 16 + ci) * 9 + s]);
  }
  const int c = lane & 15, quad = lane >> 4;
  const int ci0 = (quad & 1) * 8;
  int aoff[5];
#pragma unroll
  for (int p = 0; p < 5; ++p) {
    int s = 2 * p + (quad >> 1);
    if (s > 8) s = 8;  // address clamp; B-frag for that k-half is zero
    const int dy = s / 3, dx = s % 3;
    aoff[p] = (dy * 18 + (c + dx)) * 16 + ci0;
  }
  float ssum = 0.f, qsum = 0.f;
  for (int it = 0; it < 2; ++it) {
    __syncthreads();
    {  // stage 4 images (interior only; borders stay zero)
      const uint4* src =
          (const uint4*)(h1 + ((size_t)blockIdx.x * 8 + it * 4) * 4096);
      for (int ch = tid; ch < 2048; ch += 256) {
        const int im = ch >> 9, j = ch & 511, px = j >> 1, half = j & 1;
        const int r = px >> 4, cc = px & 15;
        *(uint4*)&hs[im * 5184 + ((r + 1) * 18 + (cc + 1)) * 16 + half * 8] =
            src[ch];
      }
    }
    __syncthreads();
    bf16x8 bf[5];
#pragma unroll
    for (int p = 0; p < 5; ++p) {
      const int s = 2 * p + (quad >> 1);  // s==9 -> wt slot 9 == zeros
      bf[p] = *(const bf16x8*)&wt[s * 256 + c * 16 + ci0];
    }
    const short* hbase = hs + wid * 5184;
    const int img = blockIdx.x * 8 + it * 4 + wid;
    float* yp = y2 + ((size_t)img * 16 + c) * 256 + quad * 4;
    for (int r = 0; r < 16; ++r) {
      f32x4 acc = {0.f, 0.f, 0.f, 0.f};
#pragma unroll
      for (int p = 0; p < 5; ++p) {
        bf16x8 a = *(const bf16x8*)&hbase[r * 288 + aoff[p]];
        acc = __builtin_amdgcn_mfma_f32_16x16x32_bf16(a, bf[p], acc, 0, 0, 0);
      }
      *(float4*)&yp[r * 16] = *(float4*)&acc;
#pragma unroll
      for (int g = 0; g < 4; ++g) { float v = acc[g]; ssum += v; qsum += v * v; }
    }
  }
  // lanes {l, l+16, l+32, l+48} share co = l&15
  ssum += __shfl_down(ssum, 32, 64); ssum += __shfl_down(ssum, 16, 64);
  qsum += __shfl_down(qsum, 32, 64); qsum += __shfl_down(qsum, 16, 64);
  if (lane < 16) { red[wid][lane] = ssum; red[wid][16 + lane] = qsum; }
  __syncthreads();
  if (tid < 32) {
    const int cc = tid & 15, isq = tid >> 4;
    float v = red[0][isq * 16 + cc] + red[1][isq * 16 + cc] +
              red[2][isq * 16 + cc] + red[3][isq * 16 + cc];
    unsafeAtomicAdd(st3 + (size_t)(2 * cc + isq) * 8, (double)v);
  }
}

__global__ __launch_bounds__(256) void k_xr2_stats(
    const float* __restrict__ y2, const float* __restrict__ g2,
    const float* __restrict__ b2, const double* __restrict__ st3,
    double* __restrict__ st4) {
  const int c = blockIdx.x & 15, n0 = (blockIdx.x >> 4) << 4;
  double sd = STG(st3, 2 * c), qd = STG(st3, 2 * c + 1);
  double md = sd / CNT2;
  float m = (float)md;
  float inv = (float)(1.0 / sqrt(qd / CNT2 - md * md + (double)EPS_BN));
  float gg = g2[c], bb = b2[c];
  float s = 0.f, q = 0.f;
#pragma unroll
  for (int k = 0; k < 16; ++k) {
    float v = y2[((size_t)(n0 + k) * 16 + c) * 256 + threadIdx.x];
    float xr = fmaxf((v - m) * inv * gg + bb, 0.f);
    s += xr; q += xr * xr;
  }
  block_stats_atomic<1>(&s, &q, st4 + (size_t)(2 * c) * 8);
}

// y2 -> BN+relu -> scale-expand -> BN+relu -> 2x2 maxpool -> h2 bf16 [4096,2048]
__global__ __launch_bounds__(256) void k_l2_out(
    const float* __restrict__ y2, const float* __restrict__ g2,
    const float* __restrict__ b2, const float* __restrict__ dsew,
    const float* __restrict__ bng, const float* __restrict__ bnb,
    const double* __restrict__ st3, const double* __restrict__ st4,
    short* __restrict__ h2) {
  __shared__ float cS3[16], cO3[16], cS4[32], cO4[32];
  const int tid = threadIdx.x;
  if (tid < 32) {
    const int i = tid >> 1, g = tid & 1;
    double sd = STG(st3, 2 * i), qd = STG(st3, 2 * i + 1);
    double md = sd / CNT2;
    float inv3 = (float)(1.0 / sqrt(qd / CNT2 - md * md + (double)EPS_BN));
    float a3 = inv3 * g2[i];
    if (g == 0) { cS3[i] = a3; cO3[i] = b2[i] - (float)md * a3; }
    double s4 = STG(st4, 2 * i), q4 = STG(st4, 2 * i + 1);
    double mx = s4 / CNT2, vx = q4 / CNT2 - mx * mx;
    float w = dsew[2 * i + g];
    double inv4 = 1.0 / sqrt((double)w * w * vx + (double)EPS_BN);
    cS4[tid] = (float)(w * inv4) * bng[tid];
    cO4[tid] = bnb[tid] - (float)(w * mx * inv4) * bng[tid];
  }
  __syncthreads();
  const int sub = tid >> 6, lane = tid & 63;
  const int n = blockIdx.x * 4 + sub;
  const int px = lane & 7, py = lane >> 3;
#pragma unroll
  for (int i = 0; i < 16; ++i) {
    const size_t base = ((size_t)n * 16 + i) * 256;
    float2 v01 = *(const float2*)&y2[base + (2 * py) * 16 + 2 * px];
    float2 v23 = *(const float2*)&y2[base + (2 * py + 1) * 16 + 2 * px];
    float a3 = cS3[i], c3 = cO3[i];
    float xr0 = fmaxf(v01.x * a3 + c3, 0.f);
    float xr1 = fmaxf(v01.y * a3 + c3, 0.f);
    float xr2 = fmaxf(v23.x * a3 + c3, 0.f);
    float xr3 = fmaxf(v23.y * a3 + c3, 0.f);
#pragma unroll
    for (int g = 0; g < 2; ++g) {
      const int c = 2 * i + g;
      float sc = cS4[c], of = cO4[c];
      float r0 = fmaxf(xr0 * sc + of, 0.f);
      float r1 = fmaxf(xr1 * sc + of, 0.f);
      float r2 = fmaxf(xr2 * sc + of, 0.f);
      float r3 = fmaxf(xr3 * sc + of, 0.f);
      h2[(size_t)n * 2048 + c * 64 + py * 8 + px] =
          f2bf(fmaxf(fmaxf(r0, r1), fmaxf(r2, r3)));
    }
  }
}

// cast fc1_w (512x2048) and fc2_w (512x512) to bf16
__global__ __launch_bounds__(256) void k_cast_w(const float* __restrict__ w1,
                                                const float* __restrict__ w2,
                                                short* __restrict__ o1,
                                                short* __restrict__ o2) {
  const int i = blockIdx.x * 256 + threadIdx.x;
  if (i < 1048576) o1[i] = f2bf(w1[i]);
  else o2[i - 1048576] = f2bf(w2[i - 1048576]);
}

// ------------- FC via MFMA: C[M,512] = act(A[M,K]bf16 @ W[512,K]bf16^T + b) --
template <int K, int RELU, int OUT_BF16>
__global__ __launch_bounds__(256) void k_fc_mfma(
    const short* __restrict__ A, const short* __restrict__ W,
    const float* __restrict__ bias, void* __restrict__ Cv) {
  const int wv = threadIdx.x >> 6, lane = threadIdx.x & 63;
  const int bm = blockIdx.y * 64;
  const int bn = blockIdx.x * 64 + wv * 16;
  const int cl = lane & 15, quad = lane >> 4;
  const short* ap = A + (size_t)(bm + cl) * K + quad * 8;
  const short* bp = W + (size_t)(bn + cl) * K + quad * 8;
  f32x4 acc0 = {0.f, 0.f, 0.f, 0.f}, acc1 = acc0, acc2 = acc0, acc3 = acc0;
#pragma unroll 4
  for (int k0 = 0; k0 < K; k0 += 32) {
    bf16x8 b = *(const bf16x8*)bp;
    bf16x8 a0 = *(const bf16x8*)ap;
    bf16x8 a1 = *(const bf16x8*)(ap + (size_t)16 * K);
    bf16x8 a2 = *(const bf16x8*)(ap + (size_t)32 * K);
    bf16x8 a3 = *(const bf16x8*)(ap + (size_t)48 * K);
    ap += 32; bp += 32;
    acc0 = __builtin_amdgcn_mfma_f32_16x16x32_bf16(a0, b, acc0, 0, 0, 0);
    acc1 = __builtin_amdgcn_mfma_f32_16x16x32_bf16(a1, b, acc1, 0, 0, 0);
    acc2 = __builtin_amdgcn_mfma_f32_16x16x32_bf16(a2, b, acc2, 0, 0, 0);
    acc3 = __builtin_amdgcn_mfma_f32_16x16x32_bf16(a3, b, acc3, 0, 0, 0);
  }
  const float bia = bias[bn + cl];
  f32x4 av[4] = {acc0, acc1, acc2, acc3};
#pragma unroll
  for (int rt = 0; rt < 4; ++rt) {
#pragma unroll
    for (int r = 0; r < 4; ++r) {
      const int row = bm + rt * 16 + quad * 4 + r;
      float v = av[rt][r] + bia;
      if (RELU) v = fmaxf(v, 0.f);
      if (OUT_BF16)
        ((short*)Cv)[(size_t)row * 512 + bn + cl] = f2bf(v);
      else
        ((float*)Cv)[(size_t)row * 512 + bn + cl] = v;
    }
  }
}

// fc3: one wave per row, N=10, K=512, fp32
__global__ __launch_bounds__(256) void k_fc3(const float* __restrict__ A,
                                             const float* __restrict__ W,
                                             const float* __restrict__ b,
                                             float* __restrict__ out) {
  const int wid = threadIdx.x >> 6, lane = threadIdx.x & 63;
  const int row = blockIdx.x * 4 + wid;
  float p[10];
#pragma unroll
  for (int o = 0; o < 10; ++o) p[o] = 0.f;
  const float* a = A + (size_t)row * 512;
#pragma unroll
  for (int jj = 0; jj < 8; ++jj) {
    const int j = lane + jj * 64;
    float av = a[j];
#pragma unroll
    for (int o = 0; o < 10; ++o) p[o] += av * W[o * 512 + j];
  }
#pragma unroll
  for (int o = 0; o < 10; ++o) p[o] = wave_sum(p[o]);
  if (lane == 0) {
#pragma unroll
    for (int o = 0; o < 10; ++o) out[(size_t)row * 10 + o] = p[o] + b[o];
  }
}

}  // namespace

extern "C" void kernel_launch(void* const* d_in, const int* in_sizes, int n_in,
                              void* d_out, int out_size, void* d_ws,
                              size_t ws_size, hipStream_t stream) {
  const float* x      = (const float*)d_in[0];
  const float* dfe1_w = (const float*)d_in[1];
  const float* dse1_g = (const float*)d_in[2];
  const float* dse1_b = (const float*)d_in[3];
  const float* dse1_w = (const float*)d_in[4];
  const float* bn1_g  = (const float*)d_in[5];
  const float* bn1_b  = (const float*)d_in[6];
  const float* dfe2_w = (const float*)d_in[7];
  const float* dse2_g = (const float*)d_in[8];
  const float* dse2_b = (const float*)d_in[9];
  const float* dse2_w = (const float*)d_in[10];
  const float* bn2_g  = (const float*)d_in[11];
  const float* bn2_b  = (const float*)d_in[12];
  const float* fc1_w  = (const float*)d_in[13];
  const float* fc1_b  = (const float*)d_in[14];
  const float* fc2_w  = (const float*)d_in[15];
  const float* fc2_b  = (const float*)d_in[16];
  const float* fc3_w  = (const float*)d_in[17];
  const float* fc3_b  = (const float*)d_in[18];
  float* out = (float*)d_out;
  char* ws = (char*)d_ws;
  short* h1 = (short*)(ws + OFF_H1);
  float* y2 = (float*)(ws + OFF_Y2);
  short* h2 = (short*)(ws + OFF_H2);
  short* a1 = (short*)(ws + OFF_A1);
  float* a2 = (float*)(ws + OFF_A2);
  short* wb1 = (short*)(ws + OFF_WB1);
  short* wb2 = (short*)(ws + OFF_WB2);
  double* st = (double*)(ws + OFF_ST);
  double* ST1 = st;
  double* ST2 = st + (size_t)16 * 8;
  double* ST3 = st + (size_t)32 * 8;
  double* ST4 = st + (size_t)64 * 8;

  hipMemsetAsync(st, 0, 96 * 8 * sizeof(double), stream);
  k_cast_w<<<5120, 256, 0, stream>>>(fc1_w, fc2_w, wb1, wb2);
  k_conv1_stats<<<512, 256, 0, stream>>>(x, dfe1_w, ST1);
  k_conv1_xr<<<512, 256, 0, stream>>>(x, dfe1_w, dse1_g, dse1_b, ST1, ST2);
  k_conv1_out<<<512, 256, 0, stream>>>(x, dfe1_w, dse1_g, dse1_b, dse1_w,
                                       bn1_g, bn1_b, ST1, ST2, h1);
  k_conv2_mfma<<<512, 256, 0, stream>>>(h1, dfe2_w, y2, ST3);
  k_xr2_stats<<<4096, 256, 0, stream>>>(y2, dse2_g, dse2_b, ST3, ST4);
  k_l2_out<<<1024, 256, 0, stream>>>(y2, dse2_g, dse2_b, dse2_w, bn2_g, bn2_b,
                                     ST3, ST4, h2);
  k_fc_mfma<2048, 1, 1><<<dim3(8, 64), 256, 0, stream>>>(h2, wb1, fc1_b, a1);
  k_fc_mfma<512, 1, 0><<<dim3(8, 64), 256, 0, stream>>>(a1, wb2, fc2_b, a2);
  k_fc3<<<1024, 256, 0, stream>>>(a2, fc3_w, fc3_b, out);
}

// Round 5
// 405.486 us; speedup vs baseline: 2.1629x; 1.1389x over previous
//
#include <hip/hip_runtime.h>
#include <math.h>

#define EPS_BN 1e-5

namespace {

constexpr double CNT1 = 4096.0 * 1024.0;  // layer1 BN count: B*32*32
constexpr double CNT2 = 4096.0 * 256.0;   // layer2 BN count: B*16*16

// workspace layout (bytes). Required ws >= ~137 MiB.
constexpr size_t OFF_H1 = 0;            // [4096,256px,16ci] bf16 = 32 MiB
constexpr size_t OFF_Y1 = 67108864;     // [4096,8,1024] f16 = 64 MiB (dies after l1_out)
constexpr size_t OFF_Y2 = 67108864;     // [4096,16,16,16] f32 = 64 MiB (aliases Y1)
constexpr size_t OFF_H2 = 0;            // [4096,2048] bf16 (reuses h1 after conv2)
constexpr size_t OFF_A1 = 33554432;     // [4096,512] bf16
constexpr size_t OFF_A2 = 41943040;     // [4096,512] f32
constexpr size_t OFF_ST = 134217728;    // BN stats: 96 slots x 64B
constexpr size_t OFF_WB1 = 134283264;   // fc1_w bf16 [512,2048] = 2 MiB
constexpr size_t OFF_WB2 = 136380416;   // fc2_w bf16 [512,512] = 0.5 MiB

#define STG(p, i) (p)[(size_t)(i) * 8]

typedef short bf16x8 __attribute__((ext_vector_type(8)));
typedef float f32x4 __attribute__((ext_vector_type(4)));
typedef _Float16 f16;
typedef _Float16 f16x2 __attribute__((ext_vector_type(2)));
typedef _Float16 f16x4 __attribute__((ext_vector_type(4)));

__device__ __forceinline__ short f2bf(float f) {
  unsigned u = __float_as_uint(f);
  u = (u + 0x7fffu + ((u >> 16) & 1u)) >> 16;
  return (short)u;
}

__device__ __forceinline__ float wave_sum(float v) {
#pragma unroll
  for (int o = 32; o > 0; o >>= 1) v += __shfl_down(v, o, 64);
  return v;
}

template <int NV>
__device__ __forceinline__ void block_stats_atomic(const float* s, const float* q,
                                                   double* __restrict__ st) {
  __shared__ float red[4][NV * 2];
  const int lane = threadIdx.x & 63, wid = threadIdx.x >> 6;
#pragma unroll
  for (int c = 0; c < NV; ++c) {
    float sv = wave_sum(s[c]);
    float qv = wave_sum(q[c]);
    if (lane == 0) { red[wid][2 * c] = sv; red[wid][2 * c + 1] = qv; }
  }
  __syncthreads();
  if (threadIdx.x < NV * 2) {
    float v = red[0][threadIdx.x] + red[1][threadIdx.x] + red[2][threadIdx.x] +
              red[3][threadIdx.x];
    unsafeAtomicAdd(st + (size_t)threadIdx.x * 8, (double)v);
  }
}

// ---------------- layer 1: conv 3x3, 3->8, on 32x32, pad 1 -------------------
__device__ __forceinline__ void conv1_stage_img(const float* __restrict__ xp,
                                                float* xs, int tid) {
  for (int i = tid; i < 3072; i += 256) {
    int ci = i >> 10, r = (i >> 5) & 31, c = i & 31;
    xs[ci * 1156 + (r + 1) * 34 + (c + 1)] = xp[i];
  }
}

__device__ __forceinline__ void conv1_compute_rows(const float* xs,
                                                   const float* wk, int tx,
                                                   int ty, float acc[4][8]) {
#pragma unroll
  for (int p = 0; p < 4; ++p)
#pragma unroll
    for (int co = 0; co < 8; ++co) acc[p][co] = 0.f;
#pragma unroll
  for (int ci = 0; ci < 3; ++ci)
#pragma unroll
    for (int dy = 0; dy < 3; ++dy)
#pragma unroll
      for (int dx = 0; dx < 3; ++dx) {
        const int j = ci * 9 + dy * 3 + dx;
        float wv[8];
        *(float4*)&wv[0] = *(const float4*)&wk[j * 8];
        *(float4*)&wv[4] = *(const float4*)&wk[j * 8 + 4];
#pragma unroll
        for (int p = 0; p < 4; ++p) {
          float xv = xs[ci * 1156 + (ty + 8 * p + dy) * 34 + (tx + dx)];
#pragma unroll
          for (int co = 0; co < 8; ++co) acc[p][co] += xv * wv[co];
        }
      }
}

// conv1 + raw-y1 stats + y1 f16 store (channel-major [n][8co][1024px]).
// 2 images per block, grid 2048.
__global__ __launch_bounds__(256) void k_conv1_y1(
    const float* __restrict__ x, const float* __restrict__ w1,
    f16* __restrict__ y1, double* __restrict__ st1) {
  __shared__ __align__(16) float xs[3 * 34 * 34];
  __shared__ __align__(16) float wk[216];
  const int tid = threadIdx.x;
  for (int i = tid; i < 3 * 34 * 34; i += 256) xs[i] = 0.f;
  if (tid < 216) wk[(tid % 27) * 8 + tid / 27] = w1[tid];
  const int tx = tid & 31, ty = tid >> 5;
  float s[8], q[8];
#pragma unroll
  for (int c = 0; c < 8; ++c) { s[c] = 0.f; q[c] = 0.f; }
  for (int img = 0; img < 2; ++img) {
    const int n = blockIdx.x * 2 + img;
    __syncthreads();
    conv1_stage_img(x + (size_t)n * 3072, xs, tid);
    __syncthreads();
    float acc[4][8];
    conv1_compute_rows(xs, wk, tx, ty, acc);
#pragma unroll
    for (int co = 0; co < 8; ++co) {
      f16* yp = y1 + ((size_t)n * 8 + co) * 1024 + ty * 32 + tx;
#pragma unroll
      for (int p = 0; p < 4; ++p) {
        float v = acc[p][co];
        s[co] += v; q[co] += v * v;
        yp[p * 256] = (f16)v;
      }
    }
  }
  block_stats_atomic<8>(s, q, st1);
}

// xr1 = relu(bn1(y1)) stats; block per (co, 16-image chunk), grid 2048
__global__ __launch_bounds__(256) void k_xr1_stats(
    const f16* __restrict__ y1, const float* __restrict__ g1,
    const float* __restrict__ b1, const double* __restrict__ st1,
    double* __restrict__ st2) {
  const int c = blockIdx.x & 7, n0 = (blockIdx.x >> 3) << 4;
  double sd = STG(st1, 2 * c), qd = STG(st1, 2 * c + 1);
  double md = sd / CNT1;
  float inv = (float)(1.0 / sqrt(qd / CNT1 - md * md + (double)EPS_BN));
  float a1 = inv * g1[c];
  float c1 = b1[c] - (float)md * a1;
  float s = 0.f, q = 0.f;
  const int tid = threadIdx.x;
#pragma unroll
  for (int k = 0; k < 16; ++k) {
    f16x4 v4 = *(const f16x4*)&y1[((size_t)(n0 + k) * 8 + c) * 1024 + tid * 4];
#pragma unroll
    for (int j = 0; j < 4; ++j) {
      float xr = fmaxf((float)v4[j] * a1 + c1, 0.f);
      s += xr; q += xr * xr;
    }
  }
  block_stats_atomic<1>(&s, &q, st2 + (size_t)(2 * c) * 8);
}

// y1 -> BN1+relu -> scale-expand -> BN2+relu -> 2x2 maxpool
// -> h1 bf16 NHWC [img][256px][16c]. 4 images per block, grid 1024.
__global__ __launch_bounds__(256) void k_l1_out(
    const f16* __restrict__ y1, const float* __restrict__ g1,
    const float* __restrict__ b1, const float* __restrict__ dsew,
    const float* __restrict__ bng, const float* __restrict__ bnb,
    const double* __restrict__ st1, const double* __restrict__ st2,
    short* __restrict__ h1) {
  __shared__ float cA1[8], cC1[8], cS2[16], cO2[16];
  const int tid = threadIdx.x;
  if (tid < 16) {
    const int i = tid >> 1, g = tid & 1;
    double sd = STG(st1, 2 * i), qd = STG(st1, 2 * i + 1);
    double md = sd / CNT1;
    float inv1 = (float)(1.0 / sqrt(qd / CNT1 - md * md + (double)EPS_BN));
    float a1 = inv1 * g1[i];
    if (g == 0) { cA1[i] = a1; cC1[i] = b1[i] - (float)md * a1; }
    double s2 = STG(st2, 2 * i), q2 = STG(st2, 2 * i + 1);
    double mx = s2 / CNT1, vx = q2 / CNT1 - mx * mx;
    float w = dsew[i * 2 + g];
    double inv2 = 1.0 / sqrt((double)w * w * vx + (double)EPS_BN);
    cS2[tid] = (float)(w * inv2) * bng[tid];
    cO2[tid] = bnb[tid] - (float)(w * mx * inv2) * bng[tid];
  }
  __syncthreads();
  const int sub = tid >> 6, lane = tid & 63;
  const int n = blockIdx.x * 4 + sub;
#pragma unroll
  for (int w = 0; w < 4; ++w) {
    const int opx = w * 64 + lane, oy = opx >> 4, ox = opx & 15;
    short hv[16];
#pragma unroll
    for (int i = 0; i < 8; ++i) {
      const size_t base = ((size_t)n * 8 + i) * 1024 + (size_t)(2 * oy) * 32 + 2 * ox;
      f16x2 v01 = *(const f16x2*)&y1[base];
      f16x2 v23 = *(const f16x2*)&y1[base + 32];
      float a1 = cA1[i], c1 = cC1[i];
      float xr0 = fmaxf((float)v01[0] * a1 + c1, 0.f);
      float xr1 = fmaxf((float)v01[1] * a1 + c1, 0.f);
      float xr2 = fmaxf((float)v23[0] * a1 + c1, 0.f);
      float xr3 = fmaxf((float)v23[1] * a1 + c1, 0.f);
#pragma unroll
      for (int g = 0; g < 2; ++g) {
        const int c = 2 * i + g;
        float sc = cS2[c], of = cO2[c];
        float r0 = fmaxf(xr0 * sc + of, 0.f);
        float r1 = fmaxf(xr1 * sc + of, 0.f);
        float r2 = fmaxf(xr2 * sc + of, 0.f);
        float r3 = fmaxf(xr3 * sc + of, 0.f);
        hv[c] = f2bf(fmaxf(fmaxf(r0, r1), fmaxf(r2, r3)));
      }
    }
    uint4* dst = (uint4*)&h1[((size_t)n * 256 + opx) * 16];
    dst[0] = ((uint4*)hv)[0];
    dst[1] = ((uint4*)hv)[1];
  }
}

// ---------------- layer 2 conv via MFMA ---------------------------------
__global__ __launch_bounds__(256) void k_conv2_mfma(
    const short* __restrict__ h1, const float* __restrict__ w2,
    float* __restrict__ y2, double* __restrict__ st3) {
  __shared__ short smem[4 * 5184 + 10 * 256];
  __shared__ float red[4][32];
  short* hs = smem;                 // 4 padded images
  short* wt = smem + 4 * 5184;      // [10][16co][16ci], slot 9 stays zero
  const int tid = threadIdx.x, wid = tid >> 6, lane = tid & 63;
  for (int i = tid; i < (4 * 5184 + 10 * 256) / 2; i += 256) ((int*)smem)[i] = 0;
  __syncthreads();
  for (int i = tid; i < 2304; i += 256) {
    const int s = i >> 8, co = (i >> 4) & 15, ci = i & 15;
    wt[i] = f2bf(w2[(co * 16 + ci) * 9 + s]);
  }
  const int c = lane & 15, quad = lane >> 4;
  const int ci0 = (quad & 1) * 8;
  int aoff[5];
#pragma unroll
  for (int p = 0; p < 5; ++p) {
    int s = 2 * p + (quad >> 1);
    if (s > 8) s = 8;  // address clamp; B-frag for that k-half is zero
    const int dy = s / 3, dx = s % 3;
    aoff[p] = (dy * 18 + (c + dx)) * 16 + ci0;
  }
  float ssum = 0.f, qsum = 0.f;
  for (int it = 0; it < 2; ++it) {
    __syncthreads();
    {  // stage 4 images (interior only; borders stay zero)
      const uint4* src =
          (const uint4*)(h1 + ((size_t)blockIdx.x * 8 + it * 4) * 4096);
      for (int ch = tid; ch < 2048; ch += 256) {
        const int im = ch >> 9, j = ch & 511, px = j >> 1, half = j & 1;
        const int r = px >> 4, cc = px & 15;
        *(uint4*)&hs[im * 5184 + ((r + 1) * 18 + (cc + 1)) * 16 + half * 8] =
            src[ch];
      }
    }
    __syncthreads();
    bf16x8 bf[5];
#pragma unroll
    for (int p = 0; p < 5; ++p) {
      const int s = 2 * p + (quad >> 1);  // s==9 -> wt slot 9 == zeros
      bf[p] = *(const bf16x8*)&wt[s * 256 + c * 16 + ci0];
    }
    const short* hbase = hs + wid * 5184;
    const int img = blockIdx.x * 8 + it * 4 + wid;
    float* yp = y2 + ((size_t)img * 16 + c) * 256 + quad * 4;
    for (int r = 0; r < 16; ++r) {
      f32x4 acc = {0.f, 0.f, 0.f, 0.f};
#pragma unroll
      for (int p = 0; p < 5; ++p) {
        bf16x8 a = *(const bf16x8*)&hbase[r * 288 + aoff[p]];
        acc = __builtin_amdgcn_mfma_f32_16x16x32_bf16(a, bf[p], acc, 0, 0, 0);
      }
      *(float4*)&yp[r * 16] = *(float4*)&acc;
#pragma unroll
      for (int g = 0; g < 4; ++g) { float v = acc[g]; ssum += v; qsum += v * v; }
    }
  }
  // lanes {l, l+16, l+32, l+48} share co = l&15
  ssum += __shfl_down(ssum, 32, 64); ssum += __shfl_down(ssum, 16, 64);
  qsum += __shfl_down(qsum, 32, 64); qsum += __shfl_down(qsum, 16, 64);
  if (lane < 16) { red[wid][lane] = ssum; red[wid][16 + lane] = qsum; }
  __syncthreads();
  if (tid < 32) {
    const int cc = tid & 15, isq = tid >> 4;
    float v = red[0][isq * 16 + cc] + red[1][isq * 16 + cc] +
              red[2][isq * 16 + cc] + red[3][isq * 16 + cc];
    unsafeAtomicAdd(st3 + (size_t)(2 * cc + isq) * 8, (double)v);
  }
}

__global__ __launch_bounds__(256) void k_xr2_stats(
    const float* __restrict__ y2, const float* __restrict__ g2,
    const float* __restrict__ b2, const double* __restrict__ st3,
    double* __restrict__ st4) {
  const int c = blockIdx.x & 15, n0 = (blockIdx.x >> 4) << 4;
  double sd = STG(st3, 2 * c), qd = STG(st3, 2 * c + 1);
  double md = sd / CNT2;
  float m = (float)md;
  float inv = (float)(1.0 / sqrt(qd / CNT2 - md * md + (double)EPS_BN));
  float gg = g2[c], bb = b2[c];
  float s = 0.f, q = 0.f;
#pragma unroll
  for (int k = 0; k < 16; ++k) {
    float v = y2[((size_t)(n0 + k) * 16 + c) * 256 + threadIdx.x];
    float xr = fmaxf((v - m) * inv * gg + bb, 0.f);
    s += xr; q += xr * xr;
  }
  block_stats_atomic<1>(&s, &q, st4 + (size_t)(2 * c) * 8);
}

// y2 -> BN+relu -> scale-expand -> BN+relu -> 2x2 maxpool -> h2 bf16 [4096,2048]
__global__ __launch_bounds__(256) void k_l2_out(
    const float* __restrict__ y2, const float* __restrict__ g2,
    const float* __restrict__ b2, const float* __restrict__ dsew,
    const float* __restrict__ bng, const float* __restrict__ bnb,
    const double* __restrict__ st3, const double* __restrict__ st4,
    short* __restrict__ h2) {
  __shared__ float cS3[16], cO3[16], cS4[32], cO4[32];
  const int tid = threadIdx.x;
  if (tid < 32) {
    const int i = tid >> 1, g = tid & 1;
    double sd = STG(st3, 2 * i), qd = STG(st3, 2 * i + 1);
    double md = sd / CNT2;
    float inv3 = (float)(1.0 / sqrt(qd / CNT2 - md * md + (double)EPS_BN));
    float a3 = inv3 * g2[i];
    if (g == 0) { cS3[i] = a3; cO3[i] = b2[i] - (float)md * a3; }
    double s4 = STG(st4, 2 * i), q4 = STG(st4, 2 * i + 1);
    double mx = s4 / CNT2, vx = q4 / CNT2 - mx * mx;
    float w = dsew[2 * i + g];
    double inv4 = 1.0 / sqrt((double)w * w * vx + (double)EPS_BN);
    cS4[tid] = (float)(w * inv4) * bng[tid];
    cO4[tid] = bnb[tid] - (float)(w * mx * inv4) * bng[tid];
  }
  __syncthreads();
  const int sub = tid >> 6, lane = tid & 63;
  const int n = blockIdx.x * 4 + sub;
  const int px = lane & 7, py = lane >> 3;
#pragma unroll
  for (int i = 0; i < 16; ++i) {
    const size_t base = ((size_t)n * 16 + i) * 256;
    float2 v01 = *(const float2*)&y2[base + (2 * py) * 16 + 2 * px];
    float2 v23 = *(const float2*)&y2[base + (2 * py + 1) * 16 + 2 * px];
    float a3 = cS3[i], c3 = cO3[i];
    float xr0 = fmaxf(v01.x * a3 + c3, 0.f);
    float xr1 = fmaxf(v01.y * a3 + c3, 0.f);
    float xr2 = fmaxf(v23.x * a3 + c3, 0.f);
    float xr3 = fmaxf(v23.y * a3 + c3, 0.f);
#pragma unroll
    for (int g = 0; g < 2; ++g) {
      const int c = 2 * i + g;
      float sc = cS4[c], of = cO4[c];
      float r0 = fmaxf(xr0 * sc + of, 0.f);
      float r1 = fmaxf(xr1 * sc + of, 0.f);
      float r2 = fmaxf(xr2 * sc + of, 0.f);
      float r3 = fmaxf(xr3 * sc + of, 0.f);
      h2[(size_t)n * 2048 + c * 64 + py * 8 + px] =
          f2bf(fmaxf(fmaxf(r0, r1), fmaxf(r2, r3)));
    }
  }
}

// cast fc1_w (512x2048) and fc2_w (512x512) to bf16
__global__ __launch_bounds__(256) void k_cast_w(const float* __restrict__ w1,
                                                const float* __restrict__ w2,
                                                short* __restrict__ o1,
                                                short* __restrict__ o2) {
  const int i = blockIdx.x * 256 + threadIdx.x;
  if (i < 1048576) o1[i] = f2bf(w1[i]);
  else o2[i - 1048576] = f2bf(w2[i - 1048576]);
}

// ------------- FC via MFMA: C[M,512] = act(A[M,K]bf16 @ W[512,K]bf16^T + b) --
template <int K, int RELU, int OUT_BF16>
__global__ __launch_bounds__(256) void k_fc_mfma(
    const short* __restrict__ A, const short* __restrict__ W,
    const float* __restrict__ bias, void* __restrict__ Cv) {
  const int wv = threadIdx.x >> 6, lane = threadIdx.x & 63;
  const int bm = blockIdx.y * 64;
  const int bn = blockIdx.x * 64 + wv * 16;
  const int cl = lane & 15, quad = lane >> 4;
  const short* ap = A + (size_t)(bm + cl) * K + quad * 8;
  const short* bp = W + (size_t)(bn + cl) * K + quad * 8;
  f32x4 acc0 = {0.f, 0.f, 0.f, 0.f}, acc1 = acc0, acc2 = acc0, acc3 = acc0;
#pragma unroll 4
  for (int k0 = 0; k0 < K; k0 += 32) {
    bf16x8 b = *(const bf16x8*)bp;
    bf16x8 a0 = *(const bf16x8*)ap;
    bf16x8 a1 = *(const bf16x8*)(ap + (size_t)16 * K);
    bf16x8 a2 = *(const bf16x8*)(ap + (size_t)32 * K);
    bf16x8 a3 = *(const bf16x8*)(ap + (size_t)48 * K);
    ap += 32; bp += 32;
    acc0 = __builtin_amdgcn_mfma_f32_16x16x32_bf16(a0, b, acc0, 0, 0, 0);
    acc1 = __builtin_amdgcn_mfma_f32_16x16x32_bf16(a1, b, acc1, 0, 0, 0);
    acc2 = __builtin_amdgcn_mfma_f32_16x16x32_bf16(a2, b, acc2, 0, 0, 0);
    acc3 = __builtin_amdgcn_mfma_f32_16x16x32_bf16(a3, b, acc3, 0, 0, 0);
  }
  const float bia = bias[bn + cl];
  f32x4 av[4] = {acc0, acc1, acc2, acc3};
#pragma unroll
  for (int rt = 0; rt < 4; ++rt) {
#pragma unroll
    for (int r = 0; r < 4; ++r) {
      const int row = bm + rt * 16 + quad * 4 + r;
      float v = av[rt][r] + bia;
      if (RELU) v = fmaxf(v, 0.f);
      if (OUT_BF16)
        ((short*)Cv)[(size_t)row * 512 + bn + cl] = f2bf(v);
      else
        ((float*)Cv)[(size_t)row * 512 + bn + cl] = v;
    }
  }
}

// fc3: one wave per row, N=10, K=512, fp32
__global__ __launch_bounds__(256) void k_fc3(const float* __restrict__ A,
                                             const float* __restrict__ W,
                                             const float* __restrict__ b,
                                             float* __restrict__ out) {
  const int wid = threadIdx.x >> 6, lane = threadIdx.x & 63;
  const int row = blockIdx.x * 4 + wid;
  float p[10];
#pragma unroll
  for (int o = 0; o < 10; ++o) p[o] = 0.f;
  const float* a = A + (size_t)row * 512;
#pragma unroll
  for (int jj = 0; jj < 8; ++jj) {
    const int j = lane + jj * 64;
    float av = a[j];
#pragma unroll
    for (int o = 0; o < 10; ++o) p[o] += av * W[o * 512 + j];
  }
#pragma unroll
  for (int o = 0; o < 10; ++o) p[o] = wave_sum(p[o]);
  if (lane == 0) {
#pragma unroll
    for (int o = 0; o < 10; ++o) out[(size_t)row * 10 + o] = p[o] + b[o];
  }
}

}  // namespace

extern "C" void kernel_launch(void* const* d_in, const int* in_sizes, int n_in,
                              void* d_out, int out_size, void* d_ws,
                              size_t ws_size, hipStream_t stream) {
  const float* x      = (const float*)d_in[0];
  const float* dfe1_w = (const float*)d_in[1];
  const float* dse1_g = (const float*)d_in[2];
  const float* dse1_b = (const float*)d_in[3];
  const float* dse1_w = (const float*)d_in[4];
  const float* bn1_g  = (const float*)d_in[5];
  const float* bn1_b  = (const float*)d_in[6];
  const float* dfe2_w = (const float*)d_in[7];
  const float* dse2_g = (const float*)d_in[8];
  const float* dse2_b = (const float*)d_in[9];
  const float* dse2_w = (const float*)d_in[10];
  const float* bn2_g  = (const float*)d_in[11];
  const float* bn2_b  = (const float*)d_in[12];
  const float* fc1_w  = (const float*)d_in[13];
  const float* fc1_b  = (const float*)d_in[14];
  const float* fc2_w  = (const float*)d_in[15];
  const float* fc2_b  = (const float*)d_in[16];
  const float* fc3_w  = (const float*)d_in[17];
  const float* fc3_b  = (const float*)d_in[18];
  float* out = (float*)d_out;
  char* ws = (char*)d_ws;
  short* h1 = (short*)(ws + OFF_H1);
  f16* y1 = (f16*)(ws + OFF_Y1);
  float* y2 = (float*)(ws + OFF_Y2);
  short* h2 = (short*)(ws + OFF_H2);
  short* a1 = (short*)(ws + OFF_A1);
  float* a2 = (float*)(ws + OFF_A2);
  short* wb1 = (short*)(ws + OFF_WB1);
  short* wb2 = (short*)(ws + OFF_WB2);
  double* st = (double*)(ws + OFF_ST);
  double* ST1 = st;
  double* ST2 = st + (size_t)16 * 8;
  double* ST3 = st + (size_t)32 * 8;
  double* ST4 = st + (size_t)64 * 8;

  hipMemsetAsync(st, 0, 96 * 8 * sizeof(double), stream);
  k_cast_w<<<5120, 256, 0, stream>>>(fc1_w, fc2_w, wb1, wb2);
  k_conv1_y1<<<2048, 256, 0, stream>>>(x, dfe1_w, y1, ST1);
  k_xr1_stats<<<2048, 256, 0, stream>>>(y1, dse1_g, dse1_b, ST1, ST2);
  k_l1_out<<<1024, 256, 0, stream>>>(y1, dse1_g, dse1_b, dse1_w, bn1_g, bn1_b,
                                     ST1, ST2, h1);
  k_conv2_mfma<<<512, 256, 0, stream>>>(h1, dfe2_w, y2, ST3);
  k_xr2_stats<<<4096, 256, 0, stream>>>(y2, dse2_g, dse2_b, ST3, ST4);
  k_l2_out<<<1024, 256, 0, stream>>>(y2, dse2_g, dse2_b, dse2_w, bn2_g, bn2_b,
                                     ST3, ST4, h2);
  k_fc_mfma<2048, 1, 1><<<dim3(8, 64), 256, 0, stream>>>(h2, wb1, fc1_b, a1);
  k_fc_mfma<512, 1, 0><<<dim3(8, 64), 256, 0, stream>>>(a1, wb2, fc2_b, a2);
  k_fc3<<<1024, 256, 0, stream>>>(a2, fc3_w, fc3_b, out);
}